// Round 1
// baseline (3090.566 us; speedup 1.0000x reference)
//
#include <hip/hip_runtime.h>
#include <hip/hip_bf16.h>
#include <math.h>

// Problem constants
#define B_  128
#define L_  256
#define E_  300
#define PF_ 50
#define D_  400      // E + 2*PF
#define D3_ 1200     // 3*D
#define C_  512
#define KW_ 3
#define R_  53
#define KDIM_ 3600   // D3 * KW
#define M_  (B_*L_)  // 32768

// ---------------- prep kernels ----------------

// Wp[q*512 + c] = conv_w[c, ch, k] with q = k*1200 + ch
__global__ void prep_wp_kernel(const float* __restrict__ conv_w, float* __restrict__ Wp) {
    int idx = blockIdx.x * blockDim.x + threadIdx.x;
    if (idx >= KDIM_ * C_) return;
    int q = idx / C_, c = idx % C_;
    int k = q / D3_, ch = q % D3_;
    Wp[idx] = conv_w[c * KDIM_ + ch * KW_ + k];
}

// Mmat[i*512 + j] = sum_r rlw[r,i] * re[r,j]
__global__ void prep_m_kernel(const float* __restrict__ rlw, const float* __restrict__ re,
                              float* __restrict__ Mmat) {
    int idx = blockIdx.x * blockDim.x + threadIdx.x;
    if (idx >= C_ * C_) return;
    int i = idx / C_, j = idx % C_;
    float acc = 0.f;
    for (int r = 0; r < R_; ++r)
        acc += rlw[r * C_ + i] * re[r * C_ + j];
    Mmat[idx] = acc;
}

// wf[b,t,d]: d<300 embed, 300..349 pos(subject_dis), 350..399 pos(object_dis)
__global__ void build_wf_kernel(const int* __restrict__ ctx, const int* __restrict__ sdis,
                                const int* __restrict__ odis, const float* __restrict__ emb,
                                const float* __restrict__ pos, float* __restrict__ wf) {
    const int total = M_ * D_;
    for (int idx = blockIdx.x * blockDim.x + threadIdx.x; idx < total;
         idx += gridDim.x * blockDim.x) {
        int d = idx % D_;
        int bt = idx / D_;
        float v;
        if (d < E_)            v = emb[(long)ctx[bt] * E_ + d];
        else if (d < E_ + PF_) v = pos[sdis[bt] * PF_ + (d - E_)];
        else                   v = pos[odis[bt] * PF_ + (d - E_ - PF_)];
        wf[idx] = v;
    }
}

// ---------------- span means + dots + softmax -> s[b,t] ----------------
__global__ __launch_bounds__(256) void attn_scale_kernel(
    const float* __restrict__ wf, const int* __restrict__ sidx, const int* __restrict__ oidx,
    float* __restrict__ s) {
    const int b = blockIdx.x;
    const int tid = threadIdx.x;
    __shared__ float subjS[D3_];
    __shared__ float objS[D3_];
    __shared__ float red[256];

    const int s0 = sidx[b * 2], s1 = sidx[b * 2 + 1];
    const int o0 = oidx[b * 2], o1 = oidx[b * 2 + 1];
    const float sinv = 1.0f / (float)(s1 - s0 + 1);
    const float oinv = 1.0f / (float)(o1 - o0 + 1);

    for (int j = 0; j < 3; ++j) {
        for (int d = tid; d < D_; d += 256) {
            float sum = 0.f;
            for (int t = s0; t <= s1; ++t) {
                int u = t + j - 1;
                if ((unsigned)u < (unsigned)L_) sum += wf[((b << 8) + u) * D_ + d];
            }
            subjS[j * D_ + d] = sum * sinv;
            float sum2 = 0.f;
            for (int t = o0; t <= o1; ++t) {
                int u = t + j - 1;
                if ((unsigned)u < (unsigned)L_) sum2 += wf[((b << 8) + u) * D_ + d];
            }
            objS[j * D_ + d] = sum2 * oinv;
        }
    }
    __syncthreads();

    // dots for position t = tid
    float ds = 0.f, dd = 0.f;
    {
        const int t = tid;
        for (int j = 0; j < 3; ++j) {
            int u = t + j - 1;
            if ((unsigned)u < (unsigned)L_) {
                const float* wrow = &wf[((b << 8) + u) * D_];
                const float* ss = &subjS[j * D_];
                const float* oo = &objS[j * D_];
                for (int d = 0; d < D_; ++d) {
                    float w = wrow[d];
                    ds += w * ss[d];
                    dd += w * oo[d];
                }
            }
        }
    }

    // softmax over the 256 threads, for ds
    red[tid] = ds; __syncthreads();
    for (int st = 128; st > 0; st >>= 1) {
        if (tid < st) red[tid] = fmaxf(red[tid], red[tid + st]);
        __syncthreads();
    }
    float ms = red[0]; __syncthreads();
    float es = expf(ds - ms);
    red[tid] = es; __syncthreads();
    for (int st = 128; st > 0; st >>= 1) {
        if (tid < st) red[tid] += red[tid + st];
        __syncthreads();
    }
    float zs = red[0]; __syncthreads();

    // softmax for dd
    red[tid] = dd; __syncthreads();
    for (int st = 128; st > 0; st >>= 1) {
        if (tid < st) red[tid] = fmaxf(red[tid], red[tid + st]);
        __syncthreads();
    }
    float mo = red[0]; __syncthreads();
    float eo = expf(dd - mo);
    red[tid] = eo; __syncthreads();
    for (int st = 128; st > 0; st >>= 1) {
        if (tid < st) red[tid] += red[tid + st];
        __syncthreads();
    }
    float zo = red[0];

    s[(b << 8) + tid] = 0.5f * (es / zs + eo / zo);
}

// ---------------- conv as implicit GEMM: sent = tanh(A @ Wp + b) ----------------
// A[m=(b,i)][q=k*1200+j*400+d] = s[b,i+k-1] * wf[b, i+k+j-2, d]  (0 out of range)
#define BM 128
#define BN 128
#define BKT 16

__global__ __launch_bounds__(256) void conv_gemm_kernel(
    const float* __restrict__ wf, const float* __restrict__ s,
    const float* __restrict__ Wp, const float* __restrict__ conv_b,
    float* __restrict__ sent) {
    __shared__ float As[BKT][BM + 4];
    __shared__ float Bs[BKT][BN + 4];
    const int tid = threadIdx.x;
    const int blockM = blockIdx.x * BM;
    const int blockN = blockIdx.y * BN;
    const int tx = tid % 16, ty = tid / 16;
    const int tq = tid % 16;   // q-lane for A staging
    const int tm0 = tid / 16;  // m base for A staging
    const int tn = tid % 128;  // n-lane for B staging
    const int tk0 = tid / 128; // kk base for B staging

    float acc[8][8] = {};

    for (int kt = 0; kt < KDIM_; kt += BKT) {
        // stage A (with fused window + scale)
        int q = kt + tq;
        int k = q / D3_;
        int r = q - k * D3_;
        int j = r / D_;
        int d = r - j * D_;
#pragma unroll
        for (int mm = 0; mm < 8; ++mm) {
            int m = tm0 + mm * 16;
            int mg = blockM + m;
            int b = mg >> 8, i = mg & 255;
            int t = i + k - 1;
            int u = t + j - 1;
            float v = 0.f;
            if ((unsigned)t < (unsigned)L_ && (unsigned)u < (unsigned)L_)
                v = s[(b << 8) + t] * wf[((b << 8) + u) * D_ + d];
            As[tq][m] = v;
        }
        // stage B
#pragma unroll
        for (int kk2 = 0; kk2 < 8; ++kk2) {
            int kk = tk0 + kk2 * 2;
            Bs[kk][tn] = Wp[(kt + kk) * C_ + blockN + tn];
        }
        __syncthreads();
#pragma unroll
        for (int kk = 0; kk < BKT; ++kk) {
            float a[8], bb[8];
#pragma unroll
            for (int ii = 0; ii < 8; ++ii) a[ii] = As[kk][ty * 8 + ii];
#pragma unroll
            for (int jj = 0; jj < 8; ++jj) bb[jj] = Bs[kk][tx * 8 + jj];
#pragma unroll
            for (int ii = 0; ii < 8; ++ii)
#pragma unroll
                for (int jj = 0; jj < 8; ++jj) acc[ii][jj] += a[ii] * bb[jj];
        }
        __syncthreads();
    }
#pragma unroll
    for (int ii = 0; ii < 8; ++ii) {
        int mg = blockM + ty * 8 + ii;
#pragma unroll
        for (int jj = 0; jj < 8; ++jj) {
            int c = blockN + tx * 8 + jj;
            sent[mg * C_ + c] = tanhf(acc[ii][jj] + conv_b[c]);
        }
    }
}

// ---------------- P = sent @ Mmat ----------------
__global__ __launch_bounds__(256) void p_gemm_kernel(
    const float* __restrict__ sent, const float* __restrict__ Mmat, float* __restrict__ P) {
    __shared__ float As[BKT][BM + 4];
    __shared__ float Bs[BKT][BN + 4];
    const int tid = threadIdx.x;
    const int blockM = blockIdx.x * BM;
    const int blockN = blockIdx.y * BN;
    const int tx = tid % 16, ty = tid / 16;
    const int tq = tid % 16;
    const int tm0 = tid / 16;
    const int tn = tid % 128;
    const int tk0 = tid / 128;

    float acc[8][8] = {};

    for (int kt = 0; kt < C_; kt += BKT) {
#pragma unroll
        for (int mm = 0; mm < 8; ++mm) {
            int m = tm0 + mm * 16;
            As[tq][m] = sent[(blockM + m) * C_ + kt + tq];
        }
#pragma unroll
        for (int kk2 = 0; kk2 < 8; ++kk2) {
            int kk = tk0 + kk2 * 2;
            Bs[kk][tn] = Mmat[(kt + kk) * C_ + blockN + tn];
        }
        __syncthreads();
#pragma unroll
        for (int kk = 0; kk < BKT; ++kk) {
            float a[8], bb[8];
#pragma unroll
            for (int ii = 0; ii < 8; ++ii) a[ii] = As[kk][ty * 8 + ii];
#pragma unroll
            for (int jj = 0; jj < 8; ++jj) bb[jj] = Bs[kk][tx * 8 + jj];
#pragma unroll
            for (int ii = 0; ii < 8; ++ii)
#pragma unroll
                for (int jj = 0; jj < 8; ++jj) acc[ii][jj] += a[ii] * bb[jj];
        }
        __syncthreads();
    }
#pragma unroll
    for (int ii = 0; ii < 8; ++ii) {
        int mg = blockM + ty * 8 + ii;
#pragma unroll
        for (int jj = 0; jj < 8; ++jj) {
            P[mg * C_ + blockN + tx * 8 + jj] = acc[ii][jj];
        }
    }
}

// ---------------- column softmax over L + weighted max -> wo[b,c] ----------------
__global__ __launch_bounds__(256) void softmax_wo_kernel(
    const float* __restrict__ P, const float* __restrict__ sent, float* __restrict__ wo) {
    const int b = blockIdx.x, tid = threadIdx.x;
    for (int c = tid; c < C_; c += 256) {
        const float* Pb = P + (long)(b << 8) * C_ + c;
        const float* Sb = sent + (long)(b << 8) * C_ + c;
        float m = -INFINITY;
        for (int l = 0; l < L_; ++l) m = fmaxf(m, Pb[l * C_]);
        float z = 0.f, wmax = -INFINITY;
        for (int l = 0; l < L_; ++l) {
            float e = expf(Pb[l * C_] - m);
            z += e;
            wmax = fmaxf(wmax, Sb[l * C_] * e);
        }
        wo[b * C_ + c] = wmax / z;
    }
}

// ---------------- normalize + distances ----------------
__global__ __launch_bounds__(256) void final_kernel(
    const float* __restrict__ wo, const float* __restrict__ re, float* __restrict__ out) {
    const int b = blockIdx.x, tid = threadIdx.x;
    __shared__ float won[C_];
    __shared__ float red[256];
    float p = 0.f;
    for (int c = tid; c < C_; c += 256) {
        float v = wo[b * C_ + c];
        p += v * v;
    }
    red[tid] = p; __syncthreads();
    for (int st = 128; st > 0; st >>= 1) {
        if (tid < st) red[tid] += red[tid + st];
        __syncthreads();
    }
    float inv = 1.f / fmaxf(sqrtf(red[0]), 1e-12f);
    for (int c = tid; c < C_; c += 256) won[c] = wo[b * C_ + c] * inv;
    __syncthreads();
    const int wv = tid >> 6, lane = tid & 63;
    for (int r = wv; r < R_; r += 4) {
        float acc2 = 0.f;
        for (int c = lane; c < C_; c += 64) {
            float dlt = won[c] - re[r * C_ + c];
            acc2 += dlt * dlt;
        }
        for (int off = 32; off > 0; off >>= 1) acc2 += __shfl_down(acc2, off);
        if (lane == 0) out[b * R_ + r] = sqrtf(acc2);
    }
}

// ---------------- launch ----------------
extern "C" void kernel_launch(void* const* d_in, const int* in_sizes, int n_in,
                              void* d_out, int out_size, void* d_ws, size_t ws_size,
                              hipStream_t stream) {
    const int* context     = (const int*)d_in[0];
    const int* subject_idx = (const int*)d_in[1];
    const int* object_idx  = (const int*)d_in[2];
    const int* subject_dis = (const int*)d_in[3];
    const int* object_dis  = (const int*)d_in[4];
    const float* embed_table = (const float*)d_in[5];
    const float* pos_table   = (const float*)d_in[6];
    const float* conv_w      = (const float*)d_in[7];
    const float* conv_b      = (const float*)d_in[8];
    const float* rlw         = (const float*)d_in[9];
    const float* re          = (const float*)d_in[10];
    float* out = (float*)d_out;

    char* ws = (char*)d_ws;
    size_t off = 0;
    auto alloc = [&](size_t bytes) {
        void* p = ws + off;
        off = (off + bytes + 255) & ~(size_t)255;
        return p;
    };
    float* wf   = (float*)alloc((size_t)M_ * D_ * 4);      // 52.4 MB
    float* s    = (float*)alloc((size_t)M_ * 4);           // 0.13 MB
    float* Wp   = (float*)alloc((size_t)KDIM_ * C_ * 4);   // 7.4 MB
    float* Mmat = (float*)alloc((size_t)C_ * C_ * 4);      // 1.0 MB
    float* sent = (float*)alloc((size_t)M_ * C_ * 4);      // 67 MB
    float* P    = (float*)alloc((size_t)M_ * C_ * 4);      // 67 MB
    float* wo   = (float*)alloc((size_t)B_ * C_ * 4);      // 0.26 MB

    // prep
    prep_wp_kernel<<<(KDIM_ * C_ + 255) / 256, 256, 0, stream>>>(conv_w, Wp);
    prep_m_kernel<<<(C_ * C_ + 255) / 256, 256, 0, stream>>>(rlw, re, Mmat);
    build_wf_kernel<<<4096, 256, 0, stream>>>(context, subject_dis, object_dis,
                                              embed_table, pos_table, wf);
    // attention scale s[b,t]
    attn_scale_kernel<<<B_, 256, 0, stream>>>(wf, subject_idx, object_idx, s);
    // conv -> sent
    conv_gemm_kernel<<<dim3(M_ / BM, C_ / BN), 256, 0, stream>>>(wf, s, Wp, conv_b, sent);
    // P = sent @ Mmat
    p_gemm_kernel<<<dim3(M_ / BM, C_ / BN), 256, 0, stream>>>(sent, Mmat, P);
    // softmax over L + weighted max
    softmax_wo_kernel<<<B_, 256, 0, stream>>>(P, sent, wo);
    // normalize + distances
    final_kernel<<<B_, 256, 0, stream>>>(wo, re, out);
}

// Round 2
// 816.148 us; speedup vs baseline: 3.7868x; 3.7868x over previous
//
#include <hip/hip_runtime.h>
#include <hip/hip_bf16.h>
#include <math.h>

// Problem constants
#define B_  128
#define L_  256
#define E_  300
#define PF_ 50
#define D_  400      // E + 2*PF
#define D3_ 1200     // 3*D
#define C_  512
#define KW_ 3
#define R_  53
#define M_  (B_*L_)  // 32768
#define KP_ 1216     // padded per-tap K (1200 -> 1216, divisible by 64)
#define K3_ (3*KP_)  // 3648 total GEMM K
#define LROWS_ 258   // L + 2 padded rows per batch in XSp

typedef __attribute__((ext_vector_type(8))) short bf16x8;
typedef __attribute__((ext_vector_type(8))) unsigned short u16x8;
typedef __attribute__((ext_vector_type(4))) float f32x4;

__device__ __forceinline__ unsigned short f2bf(float f) {
    union { float f; unsigned u; } x; x.f = f;
    unsigned r = x.u + 0x7FFF + ((x.u >> 16) & 1);
    return (unsigned short)(r >> 16);
}
__device__ __forceinline__ float bf2f(unsigned short u) {
    union { unsigned u; float f; } x; x.u = ((unsigned)u) << 16;
    return x.f;
}

__device__ __forceinline__ void gld16(const void* g, void* l) {
    __builtin_amdgcn_global_load_lds(
        (const __attribute__((address_space(1))) void*)g,
        (__attribute__((address_space(3))) void*)l, 16, 0, 0);
}

// ---------------- prep: WpT[c][q] = conv_w[c, ch, k], q = k*1216+ch, zero-pad ch>=1200
__global__ void prep_wpT_kernel(const float* __restrict__ conv_w, unsigned short* __restrict__ WpT) {
    int idx = blockIdx.x * blockDim.x + threadIdx.x;
    if (idx >= C_ * K3_) return;
    int c = idx / K3_, q = idx % K3_;
    int k = q / KP_, ch = q % KP_;
    WpT[idx] = (ch < D3_) ? f2bf(conv_w[c * (D3_ * KW_) + ch * KW_ + k]) : (unsigned short)0;
}

// ---------------- prep: MmatT[n][k] = sum_r rlw[r,k]*re[r,n]  (bf16)
__global__ void prep_mT_kernel(const float* __restrict__ rlw, const float* __restrict__ re,
                               unsigned short* __restrict__ MmatT) {
    int idx = blockIdx.x * blockDim.x + threadIdx.x;
    if (idx >= C_ * C_) return;
    int n = idx / C_, k = idx % C_;
    float acc = 0.f;
    for (int r = 0; r < R_; ++r)
        acc += rlw[r * C_ + k] * re[r * C_ + n];
    MmatT[idx] = f2bf(acc);
}

// ---------------- wf[b,t,d] f32
__global__ void build_wf_kernel(const int* __restrict__ ctx, const int* __restrict__ sdis,
                                const int* __restrict__ odis, const float* __restrict__ emb,
                                const float* __restrict__ pos, float* __restrict__ wf) {
    const int total = M_ * D_;
    for (int idx = blockIdx.x * blockDim.x + threadIdx.x; idx < total;
         idx += gridDim.x * blockDim.x) {
        int d = idx % D_;
        int bt = idx / D_;
        float v;
        if (d < E_)            v = emb[(long)ctx[bt] * E_ + d];
        else if (d < E_ + PF_) v = pos[sdis[bt] * PF_ + (d - E_)];
        else                   v = pos[odis[bt] * PF_ + (d - E_ - PF_)];
        wf[idx] = v;
    }
}

// ---------------- span means + dots + softmax -> s[b,t] (f32, unchanged)
__global__ __launch_bounds__(256) void attn_scale_kernel(
    const float* __restrict__ wf, const int* __restrict__ sidx, const int* __restrict__ oidx,
    float* __restrict__ s) {
    const int b = blockIdx.x;
    const int tid = threadIdx.x;
    __shared__ float subjS[D3_];
    __shared__ float objS[D3_];
    __shared__ float red[256];

    const int s0 = sidx[b * 2], s1 = sidx[b * 2 + 1];
    const int o0 = oidx[b * 2], o1 = oidx[b * 2 + 1];
    const float sinv = 1.0f / (float)(s1 - s0 + 1);
    const float oinv = 1.0f / (float)(o1 - o0 + 1);

    for (int j = 0; j < 3; ++j) {
        for (int d = tid; d < D_; d += 256) {
            float sum = 0.f;
            for (int t = s0; t <= s1; ++t) {
                int u = t + j - 1;
                if ((unsigned)u < (unsigned)L_) sum += wf[((b << 8) + u) * D_ + d];
            }
            subjS[j * D_ + d] = sum * sinv;
            float sum2 = 0.f;
            for (int t = o0; t <= o1; ++t) {
                int u = t + j - 1;
                if ((unsigned)u < (unsigned)L_) sum2 += wf[((b << 8) + u) * D_ + d];
            }
            objS[j * D_ + d] = sum2 * oinv;
        }
    }
    __syncthreads();

    float ds = 0.f, dd = 0.f;
    {
        const int t = tid;
        for (int j = 0; j < 3; ++j) {
            int u = t + j - 1;
            if ((unsigned)u < (unsigned)L_) {
                const float* wrow = &wf[((b << 8) + u) * D_];
                const float* ss = &subjS[j * D_];
                const float* oo = &objS[j * D_];
                for (int d = 0; d < D_; ++d) {
                    float w = wrow[d];
                    ds += w * ss[d];
                    dd += w * oo[d];
                }
            }
        }
    }

    red[tid] = ds; __syncthreads();
    for (int st = 128; st > 0; st >>= 1) {
        if (tid < st) red[tid] = fmaxf(red[tid], red[tid + st]);
        __syncthreads();
    }
    float ms = red[0]; __syncthreads();
    float es = expf(ds - ms);
    red[tid] = es; __syncthreads();
    for (int st = 128; st > 0; st >>= 1) {
        if (tid < st) red[tid] += red[tid + st];
        __syncthreads();
    }
    float zs = red[0]; __syncthreads();

    red[tid] = dd; __syncthreads();
    for (int st = 128; st > 0; st >>= 1) {
        if (tid < st) red[tid] = fmaxf(red[tid], red[tid + st]);
        __syncthreads();
    }
    float mo = red[0]; __syncthreads();
    float eo = expf(dd - mo);
    red[tid] = eo; __syncthreads();
    for (int st = 128; st > 0; st >>= 1) {
        if (tid < st) red[tid] += red[tid + st];
        __syncthreads();
    }
    float zo = red[0];

    s[(b << 8) + tid] = 0.5f * (es / zs + eo / zo);
}

// ---------------- XSp[b][row][ch] bf16: row=t+1; XSp = s[b,t]*wf3[b,t,:], zero-padded
__global__ void build_xsp_kernel(const float* __restrict__ wf, const float* __restrict__ s,
                                 unsigned short* __restrict__ XSp) {
    const int CH8 = KP_ / 8;   // 152 chunks of 8
    int idx = blockIdx.x * blockDim.x + threadIdx.x;
    const int total = B_ * LROWS_ * CH8;
    if (idx >= total) return;
    int chunk = idx % CH8;
    int rb = idx / CH8;
    int row = rb % LROWS_;
    int b = rb / LROWS_;

    u16x8 out = {0,0,0,0,0,0,0,0};
    int t = row - 1;
    int ch0 = chunk * 8;
    if ((unsigned)t < (unsigned)L_ && ch0 < D3_) {
        int j = ch0 / D_;
        int d0 = ch0 - j * D_;
        int u = t + j - 1;
        if ((unsigned)u < (unsigned)L_) {
            float sc = s[(b << 8) + t];
            const float* w = wf + ((size_t)((b << 8) + u)) * D_ + d0;
#pragma unroll
            for (int q = 0; q < 8; ++q) out[q] = f2bf(sc * w[q]);
        }
    }
    *(u16x8*)&XSp[((size_t)(b * LROWS_ + row)) * KP_ + ch0] = out;
}

// ---------------- conv as MFMA GEMM: sent = tanh(A @ WpT^T + b), A from XSp
__global__ __launch_bounds__(256) void conv_mfma_kernel(
    const unsigned short* __restrict__ XSp, const unsigned short* __restrict__ WpT,
    const float* __restrict__ conv_b, unsigned short* __restrict__ sent) {
    __shared__ unsigned short As[128 * 64];
    __shared__ unsigned short Bs[128 * 64];
    const int tid = threadIdx.x;
    const int wave = tid >> 6;
    const int lane = tid & 63;
    const int blockM = blockIdx.x * 128;
    const int blockN = blockIdx.y * 128;
    const int wr = (wave >> 1) * 64;
    const int wc = (wave & 1) * 64;
    const int srow = tid >> 3;          // 0..31 staging row base
    const int scol = (tid & 7) * 8;     // staging col in bf16 elems
    const int l15 = lane & 15;
    const int kg = (lane >> 4) * 8;

    f32x4 acc[4][4] = {};

    for (int kt = 0; kt < K3_; kt += 64) {
        int tap = kt / KP_;             // constant within chunk (KP_ % 64 == 0)
        int ch0 = kt - tap * KP_;
#pragma unroll
        for (int it = 0; it < 4; ++it) {
            int m = blockM + srow + it * 32;
            int bb = m >> 8, ii = m & 255;
            const unsigned short* ga =
                XSp + ((size_t)(bb * LROWS_ + ii + tap) * KP_ + ch0 + scol);
            gld16(ga, (char*)As + it * 4096 + wave * 1024);
            const unsigned short* gb =
                WpT + ((size_t)(blockN + srow + it * 32) * K3_ + kt + scol);
            gld16(gb, (char*)Bs + it * 4096 + wave * 1024);
        }
        __syncthreads();
#pragma unroll
        for (int ks = 0; ks < 2; ++ks) {
            bf16x8 a[4], b[4];
#pragma unroll
            for (int mi = 0; mi < 4; ++mi)
                a[mi] = *(const bf16x8*)&As[(wr + mi * 16 + l15) * 64 + ks * 32 + kg];
#pragma unroll
            for (int ni = 0; ni < 4; ++ni)
                b[ni] = *(const bf16x8*)&Bs[(wc + ni * 16 + l15) * 64 + ks * 32 + kg];
#pragma unroll
            for (int mi = 0; mi < 4; ++mi)
#pragma unroll
                for (int ni = 0; ni < 4; ++ni)
                    acc[mi][ni] = __builtin_amdgcn_mfma_f32_16x16x32_bf16(
                        a[mi], b[ni], acc[mi][ni], 0, 0, 0);
        }
        __syncthreads();
    }

    const int orow0 = (lane >> 4) * 4;
#pragma unroll
    for (int mi = 0; mi < 4; ++mi) {
#pragma unroll
        for (int ni = 0; ni < 4; ++ni) {
            int col = blockN + wc + ni * 16 + l15;
            float bias = conv_b[col];
#pragma unroll
            for (int r = 0; r < 4; ++r) {
                int row = blockM + wr + mi * 16 + orow0 + r;
                sent[(size_t)row * C_ + col] = f2bf(tanhf(acc[mi][ni][r] + bias));
            }
        }
    }
}

// ---------------- P = sent @ MmatT^T (MFMA), P f32
__global__ __launch_bounds__(256) void p_mfma_kernel(
    const unsigned short* __restrict__ sent, const unsigned short* __restrict__ MmatT,
    float* __restrict__ P) {
    __shared__ unsigned short As[128 * 64];
    __shared__ unsigned short Bs[128 * 64];
    const int tid = threadIdx.x;
    const int wave = tid >> 6;
    const int lane = tid & 63;
    const int blockM = blockIdx.x * 128;
    const int blockN = blockIdx.y * 128;
    const int wr = (wave >> 1) * 64;
    const int wc = (wave & 1) * 64;
    const int srow = tid >> 3;
    const int scol = (tid & 7) * 8;
    const int l15 = lane & 15;
    const int kg = (lane >> 4) * 8;

    f32x4 acc[4][4] = {};

    for (int kt = 0; kt < C_; kt += 64) {
#pragma unroll
        for (int it = 0; it < 4; ++it) {
            const unsigned short* ga =
                sent + ((size_t)(blockM + srow + it * 32) * C_ + kt + scol);
            gld16(ga, (char*)As + it * 4096 + wave * 1024);
            const unsigned short* gb =
                MmatT + ((size_t)(blockN + srow + it * 32) * C_ + kt + scol);
            gld16(gb, (char*)Bs + it * 4096 + wave * 1024);
        }
        __syncthreads();
#pragma unroll
        for (int ks = 0; ks < 2; ++ks) {
            bf16x8 a[4], b[4];
#pragma unroll
            for (int mi = 0; mi < 4; ++mi)
                a[mi] = *(const bf16x8*)&As[(wr + mi * 16 + l15) * 64 + ks * 32 + kg];
#pragma unroll
            for (int ni = 0; ni < 4; ++ni)
                b[ni] = *(const bf16x8*)&Bs[(wc + ni * 16 + l15) * 64 + ks * 32 + kg];
#pragma unroll
            for (int mi = 0; mi < 4; ++mi)
#pragma unroll
                for (int ni = 0; ni < 4; ++ni)
                    acc[mi][ni] = __builtin_amdgcn_mfma_f32_16x16x32_bf16(
                        a[mi], b[ni], acc[mi][ni], 0, 0, 0);
        }
        __syncthreads();
    }

    const int orow0 = (lane >> 4) * 4;
#pragma unroll
    for (int mi = 0; mi < 4; ++mi) {
#pragma unroll
        for (int ni = 0; ni < 4; ++ni) {
            int col = blockN + wc + ni * 16 + l15;
#pragma unroll
            for (int r = 0; r < 4; ++r) {
                int row = blockM + wr + mi * 16 + orow0 + r;
                P[(size_t)row * C_ + col] = acc[mi][ni][r];
            }
        }
    }
}

// ---------------- column softmax over L + weighted max -> wo[b,c]
__global__ __launch_bounds__(256) void softmax_wo_kernel(
    const float* __restrict__ P, const unsigned short* __restrict__ sent,
    float* __restrict__ wo) {
    const int b = blockIdx.x;
    const int c = blockIdx.y * 256 + threadIdx.x;
    const float* Pb = P + ((size_t)(b << 8)) * C_ + c;
    const unsigned short* Sb = sent + ((size_t)(b << 8)) * C_ + c;
    float m = -INFINITY;
    for (int l = 0; l < L_; ++l) m = fmaxf(m, Pb[(size_t)l * C_]);
    float z = 0.f, wmax = -INFINITY;
    for (int l = 0; l < L_; ++l) {
        float e = expf(Pb[(size_t)l * C_] - m);
        z += e;
        wmax = fmaxf(wmax, bf2f(Sb[(size_t)l * C_]) * e);
    }
    wo[b * C_ + c] = wmax / z;
}

// ---------------- normalize + distances
__global__ __launch_bounds__(256) void final_kernel(
    const float* __restrict__ wo, const float* __restrict__ re, float* __restrict__ out) {
    const int b = blockIdx.x, tid = threadIdx.x;
    __shared__ float won[C_];
    __shared__ float red[256];
    float p = 0.f;
    for (int c = tid; c < C_; c += 256) {
        float v = wo[b * C_ + c];
        p += v * v;
    }
    red[tid] = p; __syncthreads();
    for (int st = 128; st > 0; st >>= 1) {
        if (tid < st) red[tid] += red[tid + st];
        __syncthreads();
    }
    float inv = 1.f / fmaxf(sqrtf(red[0]), 1e-12f);
    for (int c = tid; c < C_; c += 256) won[c] = wo[b * C_ + c] * inv;
    __syncthreads();
    const int wv = tid >> 6, lane = tid & 63;
    for (int r = wv; r < R_; r += 4) {
        float acc2 = 0.f;
        for (int c = lane; c < C_; c += 64) {
            float dlt = won[c] - re[r * C_ + c];
            acc2 += dlt * dlt;
        }
        for (int off = 32; off > 0; off >>= 1) acc2 += __shfl_down(acc2, off);
        if (lane == 0) out[b * R_ + r] = sqrtf(acc2);
    }
}

// ---------------- launch ----------------
extern "C" void kernel_launch(void* const* d_in, const int* in_sizes, int n_in,
                              void* d_out, int out_size, void* d_ws, size_t ws_size,
                              hipStream_t stream) {
    const int* context     = (const int*)d_in[0];
    const int* subject_idx = (const int*)d_in[1];
    const int* object_idx  = (const int*)d_in[2];
    const int* subject_dis = (const int*)d_in[3];
    const int* object_dis  = (const int*)d_in[4];
    const float* embed_table = (const float*)d_in[5];
    const float* pos_table   = (const float*)d_in[6];
    const float* conv_w      = (const float*)d_in[7];
    const float* conv_b      = (const float*)d_in[8];
    const float* rlw         = (const float*)d_in[9];
    const float* re          = (const float*)d_in[10];
    float* out = (float*)d_out;

    char* ws = (char*)d_ws;
    size_t off = 0;
    auto alloc = [&](size_t bytes) {
        void* p = ws + off;
        off = (off + bytes + 255) & ~(size_t)255;
        return p;
    };
    float* wf            = (float*)alloc((size_t)M_ * D_ * 4);            // 52.4 MB
    float* s             = (float*)alloc((size_t)M_ * 4);                 // 0.13 MB
    unsigned short* XSp  = (unsigned short*)alloc((size_t)B_ * LROWS_ * KP_ * 2); // 80.3 MB
    unsigned short* WpT  = (unsigned short*)alloc((size_t)C_ * K3_ * 2);  // 3.7 MB
    unsigned short* MmatT= (unsigned short*)alloc((size_t)C_ * C_ * 2);   // 0.5 MB
    unsigned short* sent = (unsigned short*)alloc((size_t)M_ * C_ * 2);   // 33.6 MB
    float* wo            = (float*)alloc((size_t)B_ * C_ * 4);            // 0.26 MB
    float* P             = (float*)XSp;  // alias: XSp dead after conv_mfma; P fits in 80.3MB

    prep_wpT_kernel<<<(C_ * K3_ + 255) / 256, 256, 0, stream>>>(conv_w, WpT);
    prep_mT_kernel<<<(C_ * C_ + 255) / 256, 256, 0, stream>>>(rlw, re, MmatT);
    build_wf_kernel<<<4096, 256, 0, stream>>>(context, subject_dis, object_dis,
                                              embed_table, pos_table, wf);
    attn_scale_kernel<<<B_, 256, 0, stream>>>(wf, subject_idx, object_idx, s);
    build_xsp_kernel<<<(B_ * LROWS_ * (KP_ / 8) + 255) / 256, 256, 0, stream>>>(wf, s, XSp);
    conv_mfma_kernel<<<dim3(M_ / 128, C_ / 128), 256, 0, stream>>>(XSp, WpT, conv_b, sent);
    p_mfma_kernel<<<dim3(M_ / 128, C_ / 128), 256, 0, stream>>>(sent, MmatT, P);
    softmax_wo_kernel<<<dim3(B_, 2), 256, 0, stream>>>(P, sent, wo);
    final_kernel<<<B_, 256, 0, stream>>>(wo, re, out);
}

// Round 3
// 403.935 us; speedup vs baseline: 7.6511x; 2.0205x over previous
//
#include <hip/hip_runtime.h>
#include <hip/hip_bf16.h>
#include <math.h>

// Problem constants
#define B_  128
#define L_  256
#define E_  300
#define PF_ 50
#define D_  400      // E + 2*PF
#define D3_ 1200     // 3*D
#define C_  512
#define KW_ 3
#define R_  53
#define M_  (B_*L_)  // 32768
#define KP_ 1216     // padded per-tap K (1200 -> 1216, divisible by 64)
#define K3_ (3*KP_)  // 3648 total GEMM K
#define LROWS_ 258   // L + 2 padded rows per batch in XSp

typedef __attribute__((ext_vector_type(8))) short bf16x8;
typedef __attribute__((ext_vector_type(8))) unsigned short u16x8;
typedef __attribute__((ext_vector_type(4))) float f32x4;

__device__ __forceinline__ unsigned short f2bf(float f) {
    union { float f; unsigned u; } x; x.f = f;
    unsigned r = x.u + 0x7FFF + ((x.u >> 16) & 1);
    return (unsigned short)(r >> 16);
}
__device__ __forceinline__ float bf2f(unsigned short u) {
    union { unsigned u; float f; } x; x.u = ((unsigned)u) << 16;
    return x.f;
}

__device__ __forceinline__ void gld16(const void* g, void* l) {
    __builtin_amdgcn_global_load_lds(
        (const __attribute__((address_space(1))) void*)g,
        (__attribute__((address_space(3))) void*)l, 16, 0, 0);
}

// ---------------- prep: WpT[c][q] = conv_w[c, ch, k], q = k*1216+ch, zero-pad ch>=1200
__global__ void prep_wpT_kernel(const float* __restrict__ conv_w, unsigned short* __restrict__ WpT) {
    int idx = blockIdx.x * blockDim.x + threadIdx.x;
    if (idx >= C_ * K3_) return;
    int c = idx / K3_, q = idx % K3_;
    int k = q / KP_, ch = q % KP_;
    WpT[idx] = (ch < D3_) ? f2bf(conv_w[c * (D3_ * KW_) + ch * KW_ + k]) : (unsigned short)0;
}

// ---------------- prep: MmatT[n][k] = sum_r rlw[r,k]*re[r,n]  (bf16)
__global__ void prep_mT_kernel(const float* __restrict__ rlw, const float* __restrict__ re,
                               unsigned short* __restrict__ MmatT) {
    int idx = blockIdx.x * blockDim.x + threadIdx.x;
    if (idx >= C_ * C_) return;
    int n = idx / C_, k = idx % C_;
    float acc = 0.f;
    for (int r = 0; r < R_; ++r)
        acc += rlw[r * C_ + k] * re[r * C_ + n];
    MmatT[idx] = f2bf(acc);
}

// ---------------- wf[b,t,d] f32
__global__ void build_wf_kernel(const int* __restrict__ ctx, const int* __restrict__ sdis,
                                const int* __restrict__ odis, const float* __restrict__ emb,
                                const float* __restrict__ pos, float* __restrict__ wf) {
    const int total = M_ * D_;
    for (int idx = blockIdx.x * blockDim.x + threadIdx.x; idx < total;
         idx += gridDim.x * blockDim.x) {
        int d = idx % D_;
        int bt = idx / D_;
        float v;
        if (d < E_)            v = emb[(long)ctx[bt] * E_ + d];
        else if (d < E_ + PF_) v = pos[sdis[bt] * PF_ + (d - E_)];
        else                   v = pos[odis[bt] * PF_ + (d - E_ - PF_)];
        wf[idx] = v;
    }
}

// ---------------- Pref[b][t][d] = running sum over t of wf
__global__ void prefix_wf_kernel(const float* __restrict__ wf, float* __restrict__ Pref) {
    int idx = blockIdx.x * blockDim.x + threadIdx.x;
    if (idx >= B_ * D_) return;
    int b = idx / D_, d = idx % D_;
    const float* src = wf + (size_t)(b << 8) * D_ + d;
    float* dst = Pref + (size_t)(b << 8) * D_ + d;
    float acc = 0.f;
    for (int t = 0; t < L_; ++t) {
        acc += src[(size_t)t * D_];
        dst[(size_t)t * D_] = acc;
    }
}

// ---------------- SS[b][j][d], OS[b][j][d] span means via prefix lookups
__global__ void span_mean_kernel(const float* __restrict__ Pref,
                                 const int* __restrict__ sidx, const int* __restrict__ oidx,
                                 float* __restrict__ SS, float* __restrict__ OS) {
    int idx = blockIdx.x * blockDim.x + threadIdx.x;
    if (idx >= B_ * 3 * D_) return;
    int b = idx / (3 * D_);
    int r = idx % (3 * D_);
    int j = r / D_, d = r % D_;

    {
        int s0 = sidx[b * 2], s1 = sidx[b * 2 + 1];
        float inv = 1.f / (float)(s1 - s0 + 1);
        int lo = s0 + j - 1, hi = s1 + j - 1;
        int loc = lo < 0 ? 0 : lo;
        int hic = hi > (L_ - 1) ? (L_ - 1) : hi;
        float sum = 0.f;
        if (loc <= hic) {
            float a = Pref[((size_t)((b << 8) + hic)) * D_ + d];
            float c = (loc > 0) ? Pref[((size_t)((b << 8) + loc - 1)) * D_ + d] : 0.f;
            sum = a - c;
        }
        SS[((size_t)(b * 3 + j)) * D_ + d] = sum * inv;
    }
    {
        int s0 = oidx[b * 2], s1 = oidx[b * 2 + 1];
        float inv = 1.f / (float)(s1 - s0 + 1);
        int lo = s0 + j - 1, hi = s1 + j - 1;
        int loc = lo < 0 ? 0 : lo;
        int hic = hi > (L_ - 1) ? (L_ - 1) : hi;
        float sum = 0.f;
        if (loc <= hic) {
            float a = Pref[((size_t)((b << 8) + hic)) * D_ + d];
            float c = (loc > 0) ? Pref[((size_t)((b << 8) + loc - 1)) * D_ + d] : 0.f;
            sum = a - c;
        }
        OS[((size_t)(b * 3 + j)) * D_ + d] = sum * inv;
    }
}

// ---------------- dots: one wave per (b,t)
__global__ __launch_bounds__(256) void dots_kernel(
    const float* __restrict__ wf, const float* __restrict__ SS, const float* __restrict__ OS,
    float* __restrict__ dsb, float* __restrict__ ddb) {
    const int wave = threadIdx.x >> 6, lane = threadIdx.x & 63;
    const int g = blockIdx.x * 4 + wave;   // (b<<8)+t
    const int b = g >> 8, t = g & 255;
    float ds = 0.f, dd = 0.f;
#pragma unroll
    for (int j = 0; j < 3; ++j) {
        int u = t + j - 1;
        if ((unsigned)u < (unsigned)L_) {
            const float4* w  = (const float4*)(wf + ((size_t)((b << 8) + u)) * D_);
            const float4* ss = (const float4*)(SS + ((size_t)(b * 3 + j)) * D_);
            const float4* oo = (const float4*)(OS + ((size_t)(b * 3 + j)) * D_);
            for (int q = lane; q < D_ / 4; q += 64) {
                float4 wv = w[q], sv = ss[q], ov = oo[q];
                ds += wv.x * sv.x + wv.y * sv.y + wv.z * sv.z + wv.w * sv.w;
                dd += wv.x * ov.x + wv.y * ov.y + wv.z * ov.z + wv.w * ov.w;
            }
        }
    }
#pragma unroll
    for (int off = 32; off > 0; off >>= 1) {
        ds += __shfl_down(ds, off);
        dd += __shfl_down(dd, off);
    }
    if (lane == 0) { dsb[g] = ds; ddb[g] = dd; }
}

// ---------------- softmax over t (per b) -> s[b,t]
__global__ __launch_bounds__(256) void softmax_s_kernel(
    const float* __restrict__ dsb, const float* __restrict__ ddb, float* __restrict__ s) {
    const int b = blockIdx.x, tid = threadIdx.x;
    __shared__ float red[256];
    float ds = dsb[(b << 8) + tid];
    float dd = ddb[(b << 8) + tid];

    red[tid] = ds; __syncthreads();
    for (int st = 128; st > 0; st >>= 1) {
        if (tid < st) red[tid] = fmaxf(red[tid], red[tid + st]);
        __syncthreads();
    }
    float ms = red[0]; __syncthreads();
    float es = expf(ds - ms);
    red[tid] = es; __syncthreads();
    for (int st = 128; st > 0; st >>= 1) {
        if (tid < st) red[tid] += red[tid + st];
        __syncthreads();
    }
    float zs = red[0]; __syncthreads();

    red[tid] = dd; __syncthreads();
    for (int st = 128; st > 0; st >>= 1) {
        if (tid < st) red[tid] = fmaxf(red[tid], red[tid + st]);
        __syncthreads();
    }
    float mo = red[0]; __syncthreads();
    float eo = expf(dd - mo);
    red[tid] = eo; __syncthreads();
    for (int st = 128; st > 0; st >>= 1) {
        if (tid < st) red[tid] += red[tid + st];
        __syncthreads();
    }
    float zo = red[0];

    s[(b << 8) + tid] = 0.5f * (es / zs + eo / zo);
}

// ---------------- XSp[b][row][ch] bf16: row=t+1; XSp = s[b,t]*wf3[b,t,:], zero-padded
__global__ void build_xsp_kernel(const float* __restrict__ wf, const float* __restrict__ s,
                                 unsigned short* __restrict__ XSp) {
    const int CH8 = KP_ / 8;   // 152 chunks of 8
    int idx = blockIdx.x * blockDim.x + threadIdx.x;
    const int total = B_ * LROWS_ * CH8;
    if (idx >= total) return;
    int chunk = idx % CH8;
    int rb = idx / CH8;
    int row = rb % LROWS_;
    int b = rb / LROWS_;

    u16x8 out = {0,0,0,0,0,0,0,0};
    int t = row - 1;
    int ch0 = chunk * 8;
    if ((unsigned)t < (unsigned)L_ && ch0 < D3_) {
        int j = ch0 / D_;
        int d0 = ch0 - j * D_;
        int u = t + j - 1;
        if ((unsigned)u < (unsigned)L_) {
            float sc = s[(b << 8) + t];
            const float* w = wf + ((size_t)((b << 8) + u)) * D_ + d0;
#pragma unroll
            for (int q = 0; q < 8; ++q) out[q] = f2bf(sc * w[q]);
        }
    }
    *(u16x8*)&XSp[((size_t)(b * LROWS_ + row)) * KP_ + ch0] = out;
}

// ---------------- conv as MFMA GEMM: sent = tanh(A @ WpT^T + b), A from XSp
__global__ __launch_bounds__(256) void conv_mfma_kernel(
    const unsigned short* __restrict__ XSp, const unsigned short* __restrict__ WpT,
    const float* __restrict__ conv_b, unsigned short* __restrict__ sent) {
    __shared__ unsigned short As[128 * 64];
    __shared__ unsigned short Bs[128 * 64];
    const int tid = threadIdx.x;
    const int wave = tid >> 6;
    const int lane = tid & 63;
    const int blockM = blockIdx.x * 128;
    const int blockN = blockIdx.y * 128;
    const int wr = (wave >> 1) * 64;
    const int wc = (wave & 1) * 64;
    const int srow = tid >> 3;          // 0..31 staging row base
    const int scol = (tid & 7) * 8;     // staging col in bf16 elems
    const int l15 = lane & 15;
    const int kg = (lane >> 4) * 8;

    f32x4 acc[4][4] = {};

    for (int kt = 0; kt < K3_; kt += 64) {
        int tap = kt / KP_;             // constant within chunk (KP_ % 64 == 0)
        int ch0 = kt - tap * KP_;
#pragma unroll
        for (int it = 0; it < 4; ++it) {
            int m = blockM + srow + it * 32;
            int bb = m >> 8, ii = m & 255;
            const unsigned short* ga =
                XSp + ((size_t)(bb * LROWS_ + ii + tap) * KP_ + ch0 + scol);
            gld16(ga, (char*)As + it * 4096 + wave * 1024);
            const unsigned short* gb =
                WpT + ((size_t)(blockN + srow + it * 32) * K3_ + kt + scol);
            gld16(gb, (char*)Bs + it * 4096 + wave * 1024);
        }
        __syncthreads();
#pragma unroll
        for (int ks = 0; ks < 2; ++ks) {
            bf16x8 a[4], b[4];
#pragma unroll
            for (int mi = 0; mi < 4; ++mi)
                a[mi] = *(const bf16x8*)&As[(wr + mi * 16 + l15) * 64 + ks * 32 + kg];
#pragma unroll
            for (int ni = 0; ni < 4; ++ni)
                b[ni] = *(const bf16x8*)&Bs[(wc + ni * 16 + l15) * 64 + ks * 32 + kg];
#pragma unroll
            for (int mi = 0; mi < 4; ++mi)
#pragma unroll
                for (int ni = 0; ni < 4; ++ni)
                    acc[mi][ni] = __builtin_amdgcn_mfma_f32_16x16x32_bf16(
                        a[mi], b[ni], acc[mi][ni], 0, 0, 0);
        }
        __syncthreads();
    }

    const int orow0 = (lane >> 4) * 4;
#pragma unroll
    for (int mi = 0; mi < 4; ++mi) {
#pragma unroll
        for (int ni = 0; ni < 4; ++ni) {
            int col = blockN + wc + ni * 16 + l15;
            float bias = conv_b[col];
#pragma unroll
            for (int r = 0; r < 4; ++r) {
                int row = blockM + wr + mi * 16 + orow0 + r;
                sent[(size_t)row * C_ + col] = f2bf(tanhf(acc[mi][ni][r] + bias));
            }
        }
    }
}

// ---------------- P = sent @ MmatT^T (MFMA), P f32
__global__ __launch_bounds__(256) void p_mfma_kernel(
    const unsigned short* __restrict__ sent, const unsigned short* __restrict__ MmatT,
    float* __restrict__ P) {
    __shared__ unsigned short As[128 * 64];
    __shared__ unsigned short Bs[128 * 64];
    const int tid = threadIdx.x;
    const int wave = tid >> 6;
    const int lane = tid & 63;
    const int blockM = blockIdx.x * 128;
    const int blockN = blockIdx.y * 128;
    const int wr = (wave >> 1) * 64;
    const int wc = (wave & 1) * 64;
    const int srow = tid >> 3;
    const int scol = (tid & 7) * 8;
    const int l15 = lane & 15;
    const int kg = (lane >> 4) * 8;

    f32x4 acc[4][4] = {};

    for (int kt = 0; kt < C_; kt += 64) {
#pragma unroll
        for (int it = 0; it < 4; ++it) {
            const unsigned short* ga =
                sent + ((size_t)(blockM + srow + it * 32) * C_ + kt + scol);
            gld16(ga, (char*)As + it * 4096 + wave * 1024);
            const unsigned short* gb =
                MmatT + ((size_t)(blockN + srow + it * 32) * C_ + kt + scol);
            gld16(gb, (char*)Bs + it * 4096 + wave * 1024);
        }
        __syncthreads();
#pragma unroll
        for (int ks = 0; ks < 2; ++ks) {
            bf16x8 a[4], b[4];
#pragma unroll
            for (int mi = 0; mi < 4; ++mi)
                a[mi] = *(const bf16x8*)&As[(wr + mi * 16 + l15) * 64 + ks * 32 + kg];
#pragma unroll
            for (int ni = 0; ni < 4; ++ni)
                b[ni] = *(const bf16x8*)&Bs[(wc + ni * 16 + l15) * 64 + ks * 32 + kg];
#pragma unroll
            for (int mi = 0; mi < 4; ++mi)
#pragma unroll
                for (int ni = 0; ni < 4; ++ni)
                    acc[mi][ni] = __builtin_amdgcn_mfma_f32_16x16x32_bf16(
                        a[mi], b[ni], acc[mi][ni], 0, 0, 0);
        }
        __syncthreads();
    }

    const int orow0 = (lane >> 4) * 4;
#pragma unroll
    for (int mi = 0; mi < 4; ++mi) {
#pragma unroll
        for (int ni = 0; ni < 4; ++ni) {
            int col = blockN + wc + ni * 16 + l15;
#pragma unroll
            for (int r = 0; r < 4; ++r) {
                int row = blockM + wr + mi * 16 + orow0 + r;
                P[(size_t)row * C_ + col] = acc[mi][ni][r];
            }
        }
    }
}

// ---------------- column softmax over L + weighted max -> wo[b,c]
__global__ __launch_bounds__(256) void softmax_wo_kernel(
    const float* __restrict__ P, const unsigned short* __restrict__ sent,
    float* __restrict__ wo) {
    const int b = blockIdx.x;
    const int c = blockIdx.y * 256 + threadIdx.x;
    const float* Pb = P + ((size_t)(b << 8)) * C_ + c;
    const unsigned short* Sb = sent + ((size_t)(b << 8)) * C_ + c;
    float m = -INFINITY;
    for (int l = 0; l < L_; ++l) m = fmaxf(m, Pb[(size_t)l * C_]);
    float z = 0.f, wmax = -INFINITY;
    for (int l = 0; l < L_; ++l) {
        float e = expf(Pb[(size_t)l * C_] - m);
        z += e;
        wmax = fmaxf(wmax, bf2f(Sb[(size_t)l * C_]) * e);
    }
    wo[b * C_ + c] = wmax / z;
}

// ---------------- normalize + distances
__global__ __launch_bounds__(256) void final_kernel(
    const float* __restrict__ wo, const float* __restrict__ re, float* __restrict__ out) {
    const int b = blockIdx.x, tid = threadIdx.x;
    __shared__ float won[C_];
    __shared__ float red[256];
    float p = 0.f;
    for (int c = tid; c < C_; c += 256) {
        float v = wo[b * C_ + c];
        p += v * v;
    }
    red[tid] = p; __syncthreads();
    for (int st = 128; st > 0; st >>= 1) {
        if (tid < st) red[tid] += red[tid + st];
        __syncthreads();
    }
    float inv = 1.f / fmaxf(sqrtf(red[0]), 1e-12f);
    for (int c = tid; c < C_; c += 256) won[c] = wo[b * C_ + c] * inv;
    __syncthreads();
    const int wv = tid >> 6, lane = tid & 63;
    for (int r = wv; r < R_; r += 4) {
        float acc2 = 0.f;
        for (int c = lane; c < C_; c += 64) {
            float dlt = won[c] - re[r * C_ + c];
            acc2 += dlt * dlt;
        }
        for (int off = 32; off > 0; off >>= 1) acc2 += __shfl_down(acc2, off);
        if (lane == 0) out[b * R_ + r] = sqrtf(acc2);
    }
}

// ---------------- launch ----------------
extern "C" void kernel_launch(void* const* d_in, const int* in_sizes, int n_in,
                              void* d_out, int out_size, void* d_ws, size_t ws_size,
                              hipStream_t stream) {
    const int* context     = (const int*)d_in[0];
    const int* subject_idx = (const int*)d_in[1];
    const int* object_idx  = (const int*)d_in[2];
    const int* subject_dis = (const int*)d_in[3];
    const int* object_dis  = (const int*)d_in[4];
    const float* embed_table = (const float*)d_in[5];
    const float* pos_table   = (const float*)d_in[6];
    const float* conv_w      = (const float*)d_in[7];
    const float* conv_b      = (const float*)d_in[8];
    const float* rlw         = (const float*)d_in[9];
    const float* re          = (const float*)d_in[10];
    float* out = (float*)d_out;

    char* ws = (char*)d_ws;
    size_t off = 0;
    auto alloc = [&](size_t bytes) {
        void* p = ws + off;
        off = (off + bytes + 255) & ~(size_t)255;
        return p;
    };
    float* wf            = (float*)alloc((size_t)M_ * D_ * 4);            // 52.4 MB
    float* s             = (float*)alloc((size_t)M_ * 4);                 // 0.13 MB
    unsigned short* XSp  = (unsigned short*)alloc((size_t)B_ * LROWS_ * KP_ * 2); // 80.3 MB
    unsigned short* WpT  = (unsigned short*)alloc((size_t)C_ * K3_ * 2);  // 3.7 MB
    unsigned short* MmatT= (unsigned short*)alloc((size_t)C_ * C_ * 2);   // 0.5 MB
    unsigned short* sent = (unsigned short*)alloc((size_t)M_ * C_ * 2);   // 33.6 MB
    float* wo            = (float*)alloc((size_t)B_ * C_ * 4);            // 0.26 MB
    float* SS            = (float*)alloc((size_t)B_ * 3 * D_ * 4);        // 0.61 MB
    float* OS            = (float*)alloc((size_t)B_ * 3 * D_ * 4);        // 0.61 MB
    float* dsb           = (float*)alloc((size_t)M_ * 4);                 // 0.13 MB
    float* ddb           = (float*)alloc((size_t)M_ * 4);                 // 0.13 MB
    // aliases (sequenced so each is fully written before read, dead before overwrite):
    float* Pref = (float*)XSp;  // 52.4 MB prefix sums; dead after span_mean
    float* P    = (float*)XSp;  // 67 MB; XSp dead after conv_mfma

    prep_wpT_kernel<<<(C_ * K3_ + 255) / 256, 256, 0, stream>>>(conv_w, WpT);
    prep_mT_kernel<<<(C_ * C_ + 255) / 256, 256, 0, stream>>>(rlw, re, MmatT);
    build_wf_kernel<<<4096, 256, 0, stream>>>(context, subject_dis, object_dis,
                                              embed_table, pos_table, wf);
    // attention-scale phase (parallel)
    prefix_wf_kernel<<<(B_ * D_ + 255) / 256, 256, 0, stream>>>(wf, Pref);
    span_mean_kernel<<<(B_ * 3 * D_ + 255) / 256, 256, 0, stream>>>(Pref, subject_idx,
                                                                    object_idx, SS, OS);
    dots_kernel<<<M_ / 4, 256, 0, stream>>>(wf, SS, OS, dsb, ddb);
    softmax_s_kernel<<<B_, 256, 0, stream>>>(dsb, ddb, s);
    // conv input
    build_xsp_kernel<<<(B_ * LROWS_ * (KP_ / 8) + 255) / 256, 256, 0, stream>>>(wf, s, XSp);
    // conv -> sent
    conv_mfma_kernel<<<dim3(M_ / 128, C_ / 128), 256, 0, stream>>>(XSp, WpT, conv_b, sent);
    // P = sent @ Mmat
    p_mfma_kernel<<<dim3(M_ / 128, C_ / 128), 256, 0, stream>>>(sent, MmatT, P);
    // softmax over L + weighted max
    softmax_wo_kernel<<<dim3(B_, 2), 256, 0, stream>>>(P, sent, wo);
    // normalize + distances
    final_kernel<<<B_, 256, 0, stream>>>(wo, re, out);
}

// Round 6
// 331.945 us; speedup vs baseline: 9.3105x; 1.2169x over previous
//
#include <hip/hip_runtime.h>
#include <hip/hip_bf16.h>
#include <math.h>

// Problem constants
#define B_  128
#define L_  256
#define E_  300
#define PF_ 50
#define D_  400      // E + 2*PF
#define D3_ 1200     // 3*D
#define C_  512
#define KW_ 3
#define R_  53
#define M_  (B_*L_)  // 32768
#define KP_ 1216     // padded per-tap K (1200 -> 1216, divisible by 64)
#define K3_ (3*KP_)  // 3648 total GEMM K
#define LROWS_ 258   // L + 2 padded rows per batch in XSp

typedef __attribute__((ext_vector_type(8))) short bf16x8;
typedef __attribute__((ext_vector_type(8))) unsigned short u16x8;
typedef __attribute__((ext_vector_type(4))) float f32x4;

__device__ __forceinline__ unsigned short f2bf(float f) {
    union { float f; unsigned u; } x; x.f = f;
    unsigned r = x.u + 0x7FFF + ((x.u >> 16) & 1);
    return (unsigned short)(r >> 16);
}
__device__ __forceinline__ float bf2f(unsigned short u) {
    union { unsigned u; float f; } x; x.u = ((unsigned)u) << 16;
    return x.f;
}

__device__ __forceinline__ void gld16(const void* g, void* l) {
    __builtin_amdgcn_global_load_lds(
        (const __attribute__((address_space(1))) void*)g,
        (__attribute__((address_space(3))) void*)l, 16, 0, 0);
}

// stage one K-half plane (256 rows x 32 cols bf16, contiguous 16KB) with
// inverse-swizzled global source (T2, rule #21). 2 gld16 per thread.
__device__ __forceinline__ void stage_half(const unsigned short* g, size_t gstr,
                                           unsigned short* ldsb, int t) {
#pragma unroll
    for (int s = 0; s < 2; ++s) {
        int row = s * 128 + (t >> 2);
        int lslot = (t & 3) ^ ((t >> 2) & 3);      // row&3 == (t>>2)&3
        gld16(g + (size_t)row * gstr + lslot * 8, (char*)ldsb + s * 8192 + t * 16);
    }
}

// ---------------- prep: WpT[c][q] = conv_w[c, ch, k], q = k*1216+ch, zero-pad ch>=1200
__global__ void prep_wpT_kernel(const float* __restrict__ conv_w, unsigned short* __restrict__ WpT) {
    int idx = blockIdx.x * blockDim.x + threadIdx.x;
    if (idx >= C_ * K3_) return;
    int c = idx / K3_, q = idx % K3_;
    int k = q / KP_, ch = q % KP_;
    WpT[idx] = (ch < D3_) ? f2bf(conv_w[c * (D3_ * KW_) + ch * KW_ + k]) : (unsigned short)0;
}

// ---------------- prep: MmatT[n][k] = sum_r rlw[r,k]*re[r,n]  (bf16)
__global__ void prep_mT_kernel(const float* __restrict__ rlw, const float* __restrict__ re,
                               unsigned short* __restrict__ MmatT) {
    int idx = blockIdx.x * blockDim.x + threadIdx.x;
    if (idx >= C_ * C_) return;
    int n = idx / C_, k = idx % C_;
    float acc = 0.f;
    for (int r = 0; r < R_; ++r)
        acc += rlw[r * C_ + k] * re[r * C_ + n];
    MmatT[idx] = f2bf(acc);
}

// ---------------- wf[b,t,d] f32
__global__ void build_wf_kernel(const int* __restrict__ ctx, const int* __restrict__ sdis,
                                const int* __restrict__ odis, const float* __restrict__ emb,
                                const float* __restrict__ pos, float* __restrict__ wf) {
    const int total = M_ * D_;
    for (int idx = blockIdx.x * blockDim.x + threadIdx.x; idx < total;
         idx += gridDim.x * blockDim.x) {
        int d = idx % D_;
        int bt = idx / D_;
        float v;
        if (d < E_)            v = emb[(long)ctx[bt] * E_ + d];
        else if (d < E_ + PF_) v = pos[sdis[bt] * PF_ + (d - E_)];
        else                   v = pos[odis[bt] * PF_ + (d - E_ - PF_)];
        wf[idx] = v;
    }
}

// ---------------- Pref[b][t][d] = running sum over t of wf
__global__ void prefix_wf_kernel(const float* __restrict__ wf, float* __restrict__ Pref) {
    int idx = blockIdx.x * blockDim.x + threadIdx.x;
    if (idx >= B_ * D_) return;
    int b = idx / D_, d = idx % D_;
    const float* src = wf + (size_t)(b << 8) * D_ + d;
    float* dst = Pref + (size_t)(b << 8) * D_ + d;
    float acc = 0.f;
    for (int t = 0; t < L_; ++t) {
        acc += src[(size_t)t * D_];
        dst[(size_t)t * D_] = acc;
    }
}

// ---------------- SS[b][j][d], OS[b][j][d] span means via prefix lookups
__global__ void span_mean_kernel(const float* __restrict__ Pref,
                                 const int* __restrict__ sidx, const int* __restrict__ oidx,
                                 float* __restrict__ SS, float* __restrict__ OS) {
    int idx = blockIdx.x * blockDim.x + threadIdx.x;
    if (idx >= B_ * 3 * D_) return;
    int b = idx / (3 * D_);
    int r = idx % (3 * D_);
    int j = r / D_, d = r % D_;

    {
        int s0 = sidx[b * 2], s1 = sidx[b * 2 + 1];
        float inv = 1.f / (float)(s1 - s0 + 1);
        int lo = s0 + j - 1, hi = s1 + j - 1;
        int loc = lo < 0 ? 0 : lo;
        int hic = hi > (L_ - 1) ? (L_ - 1) : hi;
        float sum = 0.f;
        if (loc <= hic) {
            float a = Pref[((size_t)((b << 8) + hic)) * D_ + d];
            float c = (loc > 0) ? Pref[((size_t)((b << 8) + loc - 1)) * D_ + d] : 0.f;
            sum = a - c;
        }
        SS[((size_t)(b * 3 + j)) * D_ + d] = sum * inv;
    }
    {
        int s0 = oidx[b * 2], s1 = oidx[b * 2 + 1];
        float inv = 1.f / (float)(s1 - s0 + 1);
        int lo = s0 + j - 1, hi = s1 + j - 1;
        int loc = lo < 0 ? 0 : lo;
        int hic = hi > (L_ - 1) ? (L_ - 1) : hi;
        float sum = 0.f;
        if (loc <= hic) {
            float a = Pref[((size_t)((b << 8) + hic)) * D_ + d];
            float c = (loc > 0) ? Pref[((size_t)((b << 8) + loc - 1)) * D_ + d] : 0.f;
            sum = a - c;
        }
        OS[((size_t)(b * 3 + j)) * D_ + d] = sum * inv;
    }
}

// ---------------- dots: one wave per (b,t)
__global__ __launch_bounds__(256) void dots_kernel(
    const float* __restrict__ wf, const float* __restrict__ SS, const float* __restrict__ OS,
    float* __restrict__ dsb, float* __restrict__ ddb) {
    const int wave = threadIdx.x >> 6, lane = threadIdx.x & 63;
    const int g = blockIdx.x * 4 + wave;   // (b<<8)+t
    const int b = g >> 8, t = g & 255;
    float ds = 0.f, dd = 0.f;
#pragma unroll
    for (int j = 0; j < 3; ++j) {
        int u = t + j - 1;
        if ((unsigned)u < (unsigned)L_) {
            const float4* w  = (const float4*)(wf + ((size_t)((b << 8) + u)) * D_);
            const float4* ss = (const float4*)(SS + ((size_t)(b * 3 + j)) * D_);
            const float4* oo = (const float4*)(OS + ((size_t)(b * 3 + j)) * D_);
            for (int q = lane; q < D_ / 4; q += 64) {
                float4 wv = w[q], sv = ss[q], ov = oo[q];
                ds += wv.x * sv.x + wv.y * sv.y + wv.z * sv.z + wv.w * sv.w;
                dd += wv.x * ov.x + wv.y * ov.y + wv.z * ov.z + wv.w * ov.w;
            }
        }
    }
#pragma unroll
    for (int off = 32; off > 0; off >>= 1) {
        ds += __shfl_down(ds, off);
        dd += __shfl_down(dd, off);
    }
    if (lane == 0) { dsb[g] = ds; ddb[g] = dd; }
}

// ---------------- softmax over t (per b) -> s[b,t]
__global__ __launch_bounds__(256) void softmax_s_kernel(
    const float* __restrict__ dsb, const float* __restrict__ ddb, float* __restrict__ s) {
    const int b = blockIdx.x, tid = threadIdx.x;
    __shared__ float red[256];
    float ds = dsb[(b << 8) + tid];
    float dd = ddb[(b << 8) + tid];

    red[tid] = ds; __syncthreads();
    for (int st = 128; st > 0; st >>= 1) {
        if (tid < st) red[tid] = fmaxf(red[tid], red[tid + st]);
        __syncthreads();
    }
    float ms = red[0]; __syncthreads();
    float es = expf(ds - ms);
    red[tid] = es; __syncthreads();
    for (int st = 128; st > 0; st >>= 1) {
        if (tid < st) red[tid] += red[tid + st];
        __syncthreads();
    }
    float zs = red[0]; __syncthreads();

    red[tid] = dd; __syncthreads();
    for (int st = 128; st > 0; st >>= 1) {
        if (tid < st) red[tid] = fmaxf(red[tid], red[tid + st]);
        __syncthreads();
    }
    float mo = red[0]; __syncthreads();
    float eo = expf(dd - mo);
    red[tid] = eo; __syncthreads();
    for (int st = 128; st > 0; st >>= 1) {
        if (tid < st) red[tid] += red[tid + st];
        __syncthreads();
    }
    float zo = red[0];

    s[(b << 8) + tid] = 0.5f * (es / zs + eo / zo);
}

// ---------------- XSp[b][row][ch] bf16: row=t+1; XSp = s[b,t]*wf3[b,t,:], zero-padded
__global__ void build_xsp_kernel(const float* __restrict__ wf, const float* __restrict__ s,
                                 unsigned short* __restrict__ XSp) {
    const int CH8 = KP_ / 8;   // 152 chunks of 8
    int idx = blockIdx.x * blockDim.x + threadIdx.x;
    const int total = B_ * LROWS_ * CH8;
    if (idx >= total) return;
    int chunk = idx % CH8;
    int rb = idx / CH8;
    int row = rb % LROWS_;
    int b = rb / LROWS_;

    u16x8 out = {0,0,0,0,0,0,0,0};
    int t = row - 1;
    int ch0 = chunk * 8;
    if ((unsigned)t < (unsigned)L_ && ch0 < D3_) {
        int j = ch0 / D_;
        int d0 = ch0 - j * D_;
        int u = t + j - 1;
        if ((unsigned)u < (unsigned)L_) {
            float sc = s[(b << 8) + t];
            const float* w = wf + ((size_t)((b << 8) + u)) * D_ + d0;
#pragma unroll
            for (int q = 0; q < 8; ++q) out[q] = f2bf(sc * w[q]);
        }
    }
    *(u16x8*)&XSp[((size_t)(b * LROWS_ + row)) * KP_ + ch0] = out;
}

// ================= 256x256 8-phase MFMA GEMM (T2+T3+T4+T5) =================
// MODE 0: conv  — A from XSp (tap addressing), epilogue tanh(+bias) -> bf16 sent
// MODE 1: P     — A = sent, epilogue f32 -> P
// 8 waves (2M x 4N), per-wave 128x64 out. BK=64 as 2 K-half planes [256][32].
// LDS (dynamic 128KB): A[2 dbuf][2 kh][256][32] u16, then B same at +32768 u16.
// vmcnt discipline (cross-wave safety): a counted vmcnt is always followed by
// a barrier BEFORE the drained planes are read (ph1-end covers ph2's planes;
// ph3-end covers next-iter ph0's planes; prologue vmcnt+barrier covers iter-0 ph0).
template<int MODE>
__global__ __launch_bounds__(512, 2) void gemm8_kernel(
    const unsigned short* __restrict__ Aglob, const unsigned short* __restrict__ Bglob,
    const float* __restrict__ conv_b, unsigned short* __restrict__ outb,
    float* __restrict__ outf) {
    extern __shared__ unsigned short lds[];
    const int tid = threadIdx.x;
    const int lane = tid & 63;
    const int wave = tid >> 6;     // 0..7
    const int wr = wave >> 2;      // 0..1  (M half)
    const int wc = wave & 3;       // 0..3  (N quarter)
    const int bx = blockIdx.x;
    const int blockM = bx * 256;
    const int blockN = blockIdx.y * 256;
    const int l15 = lane & 15;
    const int kswz = (((lane >> 4) ^ (lane & 3)) << 3);  // swizzled 16B slot, u16 units
    const int NT = (MODE == 0) ? (K3_ / 64) : (C_ / 64);

    const size_t Astr = (MODE == 0) ? (size_t)KP_ : (size_t)C_;
    const size_t Bstr = (MODE == 0) ? (size_t)K3_ : (size_t)C_;

    auto abase = [&](int kt) -> const unsigned short* {
        if constexpr (MODE == 0) {
            int tap = kt / KP_, ch0 = kt - tap * KP_;
            return Aglob + (size_t)(bx * LROWS_ + tap) * KP_ + ch0;
        } else {
            return Aglob + (size_t)blockM * C_ + kt;
        }
    };
    auto bbase = [&](int kt) -> const unsigned short* {
        return Bglob + (size_t)blockN * Bstr + kt;
    };

    f32x4 acc[8][4] = {};

    // prologue: stage tile 0 (order A-kh0, B-kh0, A-kh1, B-kh1), then drain the
    // first two planes and barrier so ALL waves' kh0 data is resident.
    {
        const unsigned short* Ag = abase(0);
        const unsigned short* Bg = bbase(0);
        stage_half(Ag,      Astr, &lds[0],            tid);
        stage_half(Bg,      Bstr, &lds[32768],        tid);
        stage_half(Ag + 32, Astr, &lds[8192],         tid);
        stage_half(Bg + 32, Bstr, &lds[32768 + 8192], tid);
    }
    asm volatile("s_waitcnt vmcnt(4)" ::: "memory");
    __builtin_amdgcn_s_barrier();

    int cur = 0;
    for (int kt = 0; kt < NT * 64; kt += 64, cur ^= 1) {
        const int nxt = cur ^ 1;
        int ktn = kt + 64;
        if (ktn >= NT * 64) ktn = 0;               // dummy re-stage keeps vmcnt math uniform
        const unsigned short* Agn = abase(ktn);
        const unsigned short* Bgn = bbase(ktn);
        unsigned short* Alds = &lds[nxt * 16384];
        unsigned short* Blds = &lds[32768 + nxt * 16384];
        const unsigned short* Ac = &lds[cur * 16384 + (size_t)(wr * 128 + l15) * 32 + kswz];
        const unsigned short* Bc = &lds[32768 + cur * 16384 + (size_t)(wc * 64 + l15) * 32 + kswz];

        bf16x8 a[8], b0, b1;

        // ---- phase 0: kh0, n-frags 0,1 ----  (kh0 planes drained before last barrier)
#pragma unroll
        for (int mi = 0; mi < 8; ++mi) a[mi] = *(const bf16x8*)&Ac[mi * 512];
        b0 = *(const bf16x8*)&Bc[0];
        b1 = *(const bf16x8*)&Bc[512];
        stage_half(Agn, Astr, Alds, tid);
        __builtin_amdgcn_s_barrier();
        asm volatile("s_waitcnt lgkmcnt(0)" ::: "memory");
        __builtin_amdgcn_s_setprio(1);
#pragma unroll
        for (int mi = 0; mi < 8; ++mi) {
            acc[mi][0] = __builtin_amdgcn_mfma_f32_16x16x32_bf16(a[mi], b0, acc[mi][0], 0, 0, 0);
            acc[mi][1] = __builtin_amdgcn_mfma_f32_16x16x32_bf16(a[mi], b1, acc[mi][1], 0, 0, 0);
        }
        __builtin_amdgcn_s_setprio(0);
        __builtin_amdgcn_s_barrier();

        // ---- phase 1: kh0, n-frags 2,3 ----
        b0 = *(const bf16x8*)&Bc[1024];
        b1 = *(const bf16x8*)&Bc[1536];
        stage_half(Bgn, Bstr, Blds, tid);
        __builtin_amdgcn_s_barrier();
        asm volatile("s_waitcnt lgkmcnt(0)" ::: "memory");
        __builtin_amdgcn_s_setprio(1);
#pragma unroll
        for (int mi = 0; mi < 8; ++mi) {
            acc[mi][2] = __builtin_amdgcn_mfma_f32_16x16x32_bf16(a[mi], b0, acc[mi][2], 0, 0, 0);
            acc[mi][3] = __builtin_amdgcn_mfma_f32_16x16x32_bf16(a[mi], b1, acc[mi][3], 0, 0, 0);
        }
        __builtin_amdgcn_s_setprio(0);
        asm volatile("s_waitcnt vmcnt(4)" ::: "memory");   // drain kh1(cur) before barrier
        __builtin_amdgcn_s_barrier();

        // ---- phase 2: kh1, n-frags 0,1 ----  (kh1 planes drained by ALL waves above)
#pragma unroll
        for (int mi = 0; mi < 8; ++mi) a[mi] = *(const bf16x8*)&Ac[8192 + mi * 512];
        b0 = *(const bf16x8*)&Bc[8192];
        b1 = *(const bf16x8*)&Bc[8192 + 512];
        stage_half(Agn + 32, Astr, Alds + 8192, tid);
        __builtin_amdgcn_s_barrier();
        asm volatile("s_waitcnt lgkmcnt(0)" ::: "memory");
        __builtin_amdgcn_s_setprio(1);
#pragma unroll
        for (int mi = 0; mi < 8; ++mi) {
            acc[mi][0] = __builtin_amdgcn_mfma_f32_16x16x32_bf16(a[mi], b0, acc[mi][0], 0, 0, 0);
            acc[mi][1] = __builtin_amdgcn_mfma_f32_16x16x32_bf16(a[mi], b1, acc[mi][1], 0, 0, 0);
        }
        __builtin_amdgcn_s_setprio(0);
        __builtin_amdgcn_s_barrier();

        // ---- phase 3: kh1, n-frags 2,3 ----
        b0 = *(const bf16x8*)&Bc[8192 + 1024];
        b1 = *(const bf16x8*)&Bc[8192 + 1536];
        stage_half(Bgn + 32, Bstr, Blds + 8192, tid);
        __builtin_amdgcn_s_barrier();
        asm volatile("s_waitcnt lgkmcnt(0)" ::: "memory");
        __builtin_amdgcn_s_setprio(1);
#pragma unroll
        for (int mi = 0; mi < 8; ++mi) {
            acc[mi][2] = __builtin_amdgcn_mfma_f32_16x16x32_bf16(a[mi], b0, acc[mi][2], 0, 0, 0);
            acc[mi][3] = __builtin_amdgcn_mfma_f32_16x16x32_bf16(a[mi], b1, acc[mi][3], 0, 0, 0);
        }
        __builtin_amdgcn_s_setprio(0);
        asm volatile("s_waitcnt vmcnt(4)" ::: "memory");   // drain kh0(next) before barrier
        __builtin_amdgcn_s_barrier();
    }

    asm volatile("s_waitcnt vmcnt(0)" ::: "memory");  // drain dummy stage before exit

    const int r4 = ((lane >> 4) << 2);
#pragma unroll
    for (int mi = 0; mi < 8; ++mi) {
#pragma unroll
        for (int nj = 0; nj < 4; ++nj) {
            const int col = blockN + wc * 64 + nj * 16 + l15;
            const int row0 = blockM + wr * 128 + mi * 16 + r4;
            if constexpr (MODE == 0) {
                float bias = conv_b[col];
#pragma unroll
                for (int r = 0; r < 4; ++r)
                    outb[(size_t)(row0 + r) * C_ + col] = f2bf(tanhf(acc[mi][nj][r] + bias));
            } else {
#pragma unroll
                for (int r = 0; r < 4; ++r)
                    outf[(size_t)(row0 + r) * C_ + col] = acc[mi][nj][r];
            }
        }
    }
}

// ---------------- column softmax over L + weighted max -> wo[b,c]
__global__ __launch_bounds__(256) void softmax_wo_kernel(
    const float* __restrict__ P, const unsigned short* __restrict__ sent,
    float* __restrict__ wo) {
    const int b = blockIdx.x;
    const int c = blockIdx.y * 256 + threadIdx.x;
    const float* Pb = P + ((size_t)(b << 8)) * C_ + c;
    const unsigned short* Sb = sent + ((size_t)(b << 8)) * C_ + c;
    float m = -INFINITY;
    for (int l = 0; l < L_; ++l) m = fmaxf(m, Pb[(size_t)l * C_]);
    float z = 0.f, wmax = -INFINITY;
    for (int l = 0; l < L_; ++l) {
        float e = expf(Pb[(size_t)l * C_] - m);
        z += e;
        wmax = fmaxf(wmax, bf2f(Sb[(size_t)l * C_]) * e);
    }
    wo[b * C_ + c] = wmax / z;
}

// ---------------- normalize + distances
__global__ __launch_bounds__(256) void final_kernel(
    const float* __restrict__ wo, const float* __restrict__ re, float* __restrict__ out) {
    const int b = blockIdx.x, tid = threadIdx.x;
    __shared__ float won[C_];
    __shared__ float red[256];
    float p = 0.f;
    for (int c = tid; c < C_; c += 256) {
        float v = wo[b * C_ + c];
        p += v * v;
    }
    red[tid] = p; __syncthreads();
    for (int st = 128; st > 0; st >>= 1) {
        if (tid < st) red[tid] += red[tid + st];
        __syncthreads();
    }
    float inv = 1.f / fmaxf(sqrtf(red[0]), 1e-12f);
    for (int c = tid; c < C_; c += 256) won[c] = wo[b * C_ + c] * inv;
    __syncthreads();
    const int wv = tid >> 6, lane = tid & 63;
    for (int r = wv; r < R_; r += 4) {
        float acc2 = 0.f;
        for (int c = lane; c < C_; c += 64) {
            float dlt = won[c] - re[r * C_ + c];
            acc2 += dlt * dlt;
        }
        for (int off = 32; off > 0; off >>= 1) acc2 += __shfl_down(acc2, off);
        if (lane == 0) out[b * R_ + r] = sqrtf(acc2);
    }
}

// ---------------- launch ----------------
extern "C" void kernel_launch(void* const* d_in, const int* in_sizes, int n_in,
                              void* d_out, int out_size, void* d_ws, size_t ws_size,
                              hipStream_t stream) {
    const int* context     = (const int*)d_in[0];
    const int* subject_idx = (const int*)d_in[1];
    const int* object_idx  = (const int*)d_in[2];
    const int* subject_dis = (const int*)d_in[3];
    const int* object_dis  = (const int*)d_in[4];
    const float* embed_table = (const float*)d_in[5];
    const float* pos_table   = (const float*)d_in[6];
    const float* conv_w      = (const float*)d_in[7];
    const float* conv_b      = (const float*)d_in[8];
    const float* rlw         = (const float*)d_in[9];
    const float* re          = (const float*)d_in[10];
    float* out = (float*)d_out;

    char* ws = (char*)d_ws;
    size_t off = 0;
    auto alloc = [&](size_t bytes) {
        void* p = ws + off;
        off = (off + bytes + 255) & ~(size_t)255;
        return p;
    };
    float* wf            = (float*)alloc((size_t)M_ * D_ * 4);            // 52.4 MB
    float* s             = (float*)alloc((size_t)M_ * 4);                 // 0.13 MB
    unsigned short* XSp  = (unsigned short*)alloc((size_t)B_ * LROWS_ * KP_ * 2); // 80.3 MB
    unsigned short* WpT  = (unsigned short*)alloc((size_t)C_ * K3_ * 2);  // 3.7 MB
    unsigned short* MmatT= (unsigned short*)alloc((size_t)C_ * C_ * 2);   // 0.5 MB
    unsigned short* sent = (unsigned short*)alloc((size_t)M_ * C_ * 2);   // 33.6 MB
    float* wo            = (float*)alloc((size_t)B_ * C_ * 4);            // 0.26 MB
    float* SS            = (float*)alloc((size_t)B_ * 3 * D_ * 4);        // 0.61 MB
    float* OS            = (float*)alloc((size_t)B_ * 3 * D_ * 4);        // 0.61 MB
    float* dsb           = (float*)alloc((size_t)M_ * 4);                 // 0.13 MB
    float* ddb           = (float*)alloc((size_t)M_ * 4);                 // 0.13 MB
    // aliases (sequenced so each is fully written before read, dead before overwrite):
    float* Pref = (float*)XSp;  // 52.4 MB prefix sums; dead after span_mean
    float* P    = (float*)XSp;  // 67 MB; XSp dead after conv gemm

    // allow 128KB dynamic LDS for the 8-phase GEMMs (idempotent, every call)
    (void)hipFuncSetAttribute((const void*)gemm8_kernel<0>,
                              hipFuncAttributeMaxDynamicSharedMemorySize, 131072);
    (void)hipFuncSetAttribute((const void*)gemm8_kernel<1>,
                              hipFuncAttributeMaxDynamicSharedMemorySize, 131072);

    prep_wpT_kernel<<<(C_ * K3_ + 255) / 256, 256, 0, stream>>>(conv_w, WpT);
    prep_mT_kernel<<<(C_ * C_ + 255) / 256, 256, 0, stream>>>(rlw, re, MmatT);
    build_wf_kernel<<<4096, 256, 0, stream>>>(context, subject_dis, object_dis,
                                              embed_table, pos_table, wf);
    // attention-scale phase (parallel)
    prefix_wf_kernel<<<(B_ * D_ + 255) / 256, 256, 0, stream>>>(wf, Pref);
    span_mean_kernel<<<(B_ * 3 * D_ + 255) / 256, 256, 0, stream>>>(Pref, subject_idx,
                                                                    object_idx, SS, OS);
    dots_kernel<<<M_ / 4, 256, 0, stream>>>(wf, SS, OS, dsb, ddb);
    softmax_s_kernel<<<B_, 256, 0, stream>>>(dsb, ddb, s);
    // conv input
    build_xsp_kernel<<<(B_ * LROWS_ * (KP_ / 8) + 255) / 256, 256, 0, stream>>>(wf, s, XSp);
    // conv -> sent (8-phase MFMA)
    gemm8_kernel<0><<<dim3(M_ / 256, C_ / 256), 512, 131072, stream>>>(
        XSp, WpT, conv_b, sent, nullptr);
    // P = sent @ Mmat (8-phase MFMA)
    gemm8_kernel<1><<<dim3(M_ / 256, C_ / 256), 512, 131072, stream>>>(
        sent, MmatT, nullptr, nullptr, P);
    // softmax over L + weighted max
    softmax_wo_kernel<<<dim3(B_, 2), 256, 0, stream>>>(P, sent, wo);
    // normalize + distances
    final_kernel<<<B_, 256, 0, stream>>>(wo, re, out);
}

// Round 7
// 315.008 us; speedup vs baseline: 9.8111x; 1.0538x over previous
//
#include <hip/hip_runtime.h>
#include <hip/hip_bf16.h>
#include <math.h>

// Problem constants
#define B_  128
#define L_  256
#define E_  300
#define PF_ 50
#define D_  400      // E + 2*PF
#define D3_ 1200     // 3*D
#define C_  512
#define KW_ 3
#define R_  53
#define M_  (B_*L_)  // 32768
#define KP_ 1216     // padded per-tap K (1200 -> 1216, divisible by 64)
#define K3_ (3*KP_)  // 3648 total GEMM K
#define LROWS_ 258   // L + 2 padded rows per batch in XSp

typedef __attribute__((ext_vector_type(8))) short bf16x8;
typedef __attribute__((ext_vector_type(8))) unsigned short u16x8;
typedef __attribute__((ext_vector_type(4))) float f32x4;

__device__ __forceinline__ unsigned short f2bf(float f) {
    union { float f; unsigned u; } x; x.f = f;
    unsigned r = x.u + 0x7FFF + ((x.u >> 16) & 1);
    return (unsigned short)(r >> 16);
}
__device__ __forceinline__ float bf2f(unsigned short u) {
    union { unsigned u; float f; } x; x.u = ((unsigned)u) << 16;
    return x.f;
}

__device__ __forceinline__ void gld16(const void* g, void* l) {
    __builtin_amdgcn_global_load_lds(
        (const __attribute__((address_space(1))) void*)g,
        (__attribute__((address_space(3))) void*)l, 16, 0, 0);
}

// ---------------- prep: WpT[c][q] = conv_w[c, ch, k], q = k*1216+ch, zero-pad ch>=1200
__global__ void prep_wpT_kernel(const float* __restrict__ conv_w, unsigned short* __restrict__ WpT) {
    int idx = blockIdx.x * blockDim.x + threadIdx.x;
    if (idx >= C_ * K3_) return;
    int c = idx / K3_, q = idx % K3_;
    int k = q / KP_, ch = q % KP_;
    WpT[idx] = (ch < D3_) ? f2bf(conv_w[c * (D3_ * KW_) + ch * KW_ + k]) : (unsigned short)0;
}

// ---------------- prep: MmatT[n][k] = sum_r rlw[r,k]*re[r,n]  (bf16)
__global__ void prep_mT_kernel(const float* __restrict__ rlw, const float* __restrict__ re,
                               unsigned short* __restrict__ MmatT) {
    int idx = blockIdx.x * blockDim.x + threadIdx.x;
    if (idx >= C_ * C_) return;
    int n = idx / C_, k = idx % C_;
    float acc = 0.f;
    for (int r = 0; r < R_; ++r)
        acc += rlw[r * C_ + k] * re[r * C_ + n];
    MmatT[idx] = f2bf(acc);
}

// ---------------- wf[b,t,d] f32
__global__ void build_wf_kernel(const int* __restrict__ ctx, const int* __restrict__ sdis,
                                const int* __restrict__ odis, const float* __restrict__ emb,
                                const float* __restrict__ pos, float* __restrict__ wf) {
    const int total = M_ * D_;
    for (int idx = blockIdx.x * blockDim.x + threadIdx.x; idx < total;
         idx += gridDim.x * blockDim.x) {
        int d = idx % D_;
        int bt = idx / D_;
        float v;
        if (d < E_)            v = emb[(long)ctx[bt] * E_ + d];
        else if (d < E_ + PF_) v = pos[sdis[bt] * PF_ + (d - E_)];
        else                   v = pos[odis[bt] * PF_ + (d - E_ - PF_)];
        wf[idx] = v;
    }
}

// ---------------- Pref[b][t][d] = running sum over t of wf
__global__ void prefix_wf_kernel(const float* __restrict__ wf, float* __restrict__ Pref) {
    int idx = blockIdx.x * blockDim.x + threadIdx.x;
    if (idx >= B_ * D_) return;
    int b = idx / D_, d = idx % D_;
    const float* src = wf + (size_t)(b << 8) * D_ + d;
    float* dst = Pref + (size_t)(b << 8) * D_ + d;
    float acc = 0.f;
    for (int t = 0; t < L_; ++t) {
        acc += src[(size_t)t * D_];
        dst[(size_t)t * D_] = acc;
    }
}

// ---------------- SS[b][j][d], OS[b][j][d] span means via prefix lookups
__global__ void span_mean_kernel(const float* __restrict__ Pref,
                                 const int* __restrict__ sidx, const int* __restrict__ oidx,
                                 float* __restrict__ SS, float* __restrict__ OS) {
    int idx = blockIdx.x * blockDim.x + threadIdx.x;
    if (idx >= B_ * 3 * D_) return;
    int b = idx / (3 * D_);
    int r = idx % (3 * D_);
    int j = r / D_, d = r % D_;

    {
        int s0 = sidx[b * 2], s1 = sidx[b * 2 + 1];
        float inv = 1.f / (float)(s1 - s0 + 1);
        int lo = s0 + j - 1, hi = s1 + j - 1;
        int loc = lo < 0 ? 0 : lo;
        int hic = hi > (L_ - 1) ? (L_ - 1) : hi;
        float sum = 0.f;
        if (loc <= hic) {
            float a = Pref[((size_t)((b << 8) + hic)) * D_ + d];
            float c = (loc > 0) ? Pref[((size_t)((b << 8) + loc - 1)) * D_ + d] : 0.f;
            sum = a - c;
        }
        SS[((size_t)(b * 3 + j)) * D_ + d] = sum * inv;
    }
    {
        int s0 = oidx[b * 2], s1 = oidx[b * 2 + 1];
        float inv = 1.f / (float)(s1 - s0 + 1);
        int lo = s0 + j - 1, hi = s1 + j - 1;
        int loc = lo < 0 ? 0 : lo;
        int hic = hi > (L_ - 1) ? (L_ - 1) : hi;
        float sum = 0.f;
        if (loc <= hic) {
            float a = Pref[((size_t)((b << 8) + hic)) * D_ + d];
            float c = (loc > 0) ? Pref[((size_t)((b << 8) + loc - 1)) * D_ + d] : 0.f;
            sum = a - c;
        }
        OS[((size_t)(b * 3 + j)) * D_ + d] = sum * inv;
    }
}

// ---------------- dots: one wave per (b,t)
__global__ __launch_bounds__(256) void dots_kernel(
    const float* __restrict__ wf, const float* __restrict__ SS, const float* __restrict__ OS,
    float* __restrict__ dsb, float* __restrict__ ddb) {
    const int wave = threadIdx.x >> 6, lane = threadIdx.x & 63;
    const int g = blockIdx.x * 4 + wave;   // (b<<8)+t
    const int b = g >> 8, t = g & 255;
    float ds = 0.f, dd = 0.f;
#pragma unroll
    for (int j = 0; j < 3; ++j) {
        int u = t + j - 1;
        if ((unsigned)u < (unsigned)L_) {
            const float4* w  = (const float4*)(wf + ((size_t)((b << 8) + u)) * D_);
            const float4* ss = (const float4*)(SS + ((size_t)(b * 3 + j)) * D_);
            const float4* oo = (const float4*)(OS + ((size_t)(b * 3 + j)) * D_);
            for (int q = lane; q < D_ / 4; q += 64) {
                float4 wv = w[q], sv = ss[q], ov = oo[q];
                ds += wv.x * sv.x + wv.y * sv.y + wv.z * sv.z + wv.w * sv.w;
                dd += wv.x * ov.x + wv.y * ov.y + wv.z * ov.z + wv.w * ov.w;
            }
        }
    }
#pragma unroll
    for (int off = 32; off > 0; off >>= 1) {
        ds += __shfl_down(ds, off);
        dd += __shfl_down(dd, off);
    }
    if (lane == 0) { dsb[g] = ds; ddb[g] = dd; }
}

// ---------------- softmax over t (per b) -> s[b,t]
__global__ __launch_bounds__(256) void softmax_s_kernel(
    const float* __restrict__ dsb, const float* __restrict__ ddb, float* __restrict__ s) {
    const int b = blockIdx.x, tid = threadIdx.x;
    __shared__ float red[256];
    float ds = dsb[(b << 8) + tid];
    float dd = ddb[(b << 8) + tid];

    red[tid] = ds; __syncthreads();
    for (int st = 128; st > 0; st >>= 1) {
        if (tid < st) red[tid] = fmaxf(red[tid], red[tid + st]);
        __syncthreads();
    }
    float ms = red[0]; __syncthreads();
    float es = expf(ds - ms);
    red[tid] = es; __syncthreads();
    for (int st = 128; st > 0; st >>= 1) {
        if (tid < st) red[tid] += red[tid + st];
        __syncthreads();
    }
    float zs = red[0]; __syncthreads();

    red[tid] = dd; __syncthreads();
    for (int st = 128; st > 0; st >>= 1) {
        if (tid < st) red[tid] = fmaxf(red[tid], red[tid + st]);
        __syncthreads();
    }
    float mo = red[0]; __syncthreads();
    float eo = expf(dd - mo);
    red[tid] = eo; __syncthreads();
    for (int st = 128; st > 0; st >>= 1) {
        if (tid < st) red[tid] += red[tid + st];
        __syncthreads();
    }
    float zo = red[0];

    s[(b << 8) + tid] = 0.5f * (es / zs + eo / zo);
}

// ---------------- XSp[b][row][ch] bf16: row=t+1; XSp = s[b,t]*wf3[b,t,:], zero-padded
__global__ void build_xsp_kernel(const float* __restrict__ wf, const float* __restrict__ s,
                                 unsigned short* __restrict__ XSp) {
    const int CH8 = KP_ / 8;   // 152 chunks of 8
    int idx = blockIdx.x * blockDim.x + threadIdx.x;
    const int total = B_ * LROWS_ * CH8;
    if (idx >= total) return;
    int chunk = idx % CH8;
    int rb = idx / CH8;
    int row = rb % LROWS_;
    int b = rb / LROWS_;

    u16x8 out = {0,0,0,0,0,0,0,0};
    int t = row - 1;
    int ch0 = chunk * 8;
    if ((unsigned)t < (unsigned)L_ && ch0 < D3_) {
        int j = ch0 / D_;
        int d0 = ch0 - j * D_;
        int u = t + j - 1;
        if ((unsigned)u < (unsigned)L_) {
            float sc = s[(b << 8) + t];
            const float* w = wf + ((size_t)((b << 8) + u)) * D_ + d0;
#pragma unroll
            for (int q = 0; q < 8; ++q) out[q] = f2bf(sc * w[q]);
        }
    }
    *(u16x8*)&XSp[((size_t)(b * LROWS_ + row)) * KP_ + ch0] = out;
}

// ============ 256x256 role-split MFMA GEMM (T1-lite/T2/T5, 1 barrier/tile) ============
// MODE 0: conv  — A from XSp (tap addressing), epilogue tanh(+bias) -> bf16 sent
// MODE 1: P     — A = sent, epilogue f32 -> P
// 8 waves = 2M x 4N; per-wave out 128x64. BK=64.
// LDS planes (16KB each): A[2 dbuf][2 Mhalf][128 rows][64 k], B[2 dbuf][2 Nhalf][128 cols][64 k].
// Each wave stages ONLY its own (A-half[wr], B-half[wc>>1]) planes (4+4 gld16/tile) and
// reads only those planes -> genuine role-split, no per-phase barriers.
// Swizzle (T2, rule #21 both-sides): 16B slot p at row r holds global k-slot p^(r&7);
// reads use slot ((lane>>4)+kh*4)^(row&7) -> 8 distinct bank groups, conflict-free.
// Sync: ONE __syncthreads() per K-tile (implicit vmcnt(0)+lgkmcnt(0) is the intended
// boundary drain: own stage loads are ~3 steps old by then). ds_read<->MFMA ordering
// within a tile is by register data-dependence + compiler's counted lgkmcnt.
template<int MODE>
__global__ __launch_bounds__(512, 2) void gemm8_kernel(
    const unsigned short* __restrict__ Aglob, const unsigned short* __restrict__ Bglob,
    const float* __restrict__ conv_b, unsigned short* __restrict__ outb,
    float* __restrict__ outf) {
    extern __shared__ unsigned short lds[];
    const int tid = threadIdx.x;
    const int lane = tid & 63;
    const int wave = tid >> 6;     // 0..7
    const int wr = wave >> 2;      // 0..1  (M half)
    const int wc = wave & 3;       // 0..3  (N quarter)
    const int bx = blockIdx.x;
    const int blockN = blockIdx.y * 256;
    const int l15 = lane & 15;
    const int NT = (MODE == 0) ? (K3_ / 64) : (C_ / 64);
    const size_t Astr = (MODE == 0) ? (size_t)KP_ : (size_t)C_;
    const size_t Bstr = (MODE == 0) ? (size_t)K3_ : (size_t)C_;

    const int arole = wc;              // this wave's staging role within A-half[wr]
    const int bhalf = wc >> 1;         // B N-half this wave consumes
    const int brole = wr * 2 + (wc & 1);

    // read-side swizzled 16B-slot offsets (u16 units): slot g=(lane>>4)+kh*4, XOR row&7
    const int acol0 = (((lane >> 4) + 0) ^ (l15 & 7)) * 8;   // kh0
    const int acol1 = (((lane >> 4) + 4) ^ (l15 & 7)) * 8;   // kh1
    const int bro = (wc & 1) * 64;     // col base inside B-half

    // stage one plane quarter (role r): 4 gld16, slots r*256+i*64+lane
    auto stageA = [&](int kt, int buf) {
        const unsigned short* gb;
        if constexpr (MODE == 0) {
            int tap = kt / KP_, ch0 = kt - tap * KP_;
            gb = Aglob + ((size_t)(bx * LROWS_ + wr * 128 + tap)) * KP_ + ch0;
        } else {
            gb = Aglob + ((size_t)(bx * 256 + wr * 128)) * C_ + kt;
        }
        unsigned short* pb = &lds[(buf * 2 + wr) * 8192];
#pragma unroll
        for (int i = 0; i < 4; ++i) {
            int sl = arole * 256 + i * 64 + lane;
            int row = sl >> 3, p = sl & 7;
            int colg = p ^ (row & 7);
            gld16(gb + (size_t)row * Astr + colg * 8, (char*)pb + sl * 16);
        }
    };
    auto stageB = [&](int kt, int buf) {
        const unsigned short* gb = Bglob + ((size_t)(blockN + bhalf * 128)) * Bstr + kt;
        unsigned short* pb = &lds[32768 + (buf * 2 + bhalf) * 8192];
#pragma unroll
        for (int i = 0; i < 4; ++i) {
            int sl = brole * 256 + i * 64 + lane;
            int row = sl >> 3, p = sl & 7;
            int colg = p ^ (row & 7);
            gld16(gb + (size_t)row * Bstr + colg * 8, (char*)pb + sl * 16);
        }
    };

    f32x4 acc[8][4] = {};

    // prologue: stage tile 0 into buf 0; __syncthreads drains (vmcnt 0) + barriers.
    stageA(0, 0);
    stageB(0, 0);
    __syncthreads();

    int cur = 0;
    for (int kt = 0; kt < NT * 64; kt += 64, cur ^= 1) {
        int ktn = kt + 64;
        if (ktn >= NT * 64) ktn = 0;           // dummy re-stage on last tile (drained at boundary)
        const unsigned short* Ap = &lds[(cur * 2 + wr) * 8192];
        const unsigned short* Bp = &lds[32768 + (cur * 2 + bhalf) * 8192];

        bf16x8 a[8], b0, b1;

        // ---- step 0: kh0, n-frags 0,1 ----
#pragma unroll
        for (int mi = 0; mi < 8; ++mi) a[mi] = *(const bf16x8*)&Ap[(mi * 16 + l15) * 64 + acol0];
        b0 = *(const bf16x8*)&Bp[(bro + 0 * 16 + l15) * 64 + acol0];
        b1 = *(const bf16x8*)&Bp[(bro + 1 * 16 + l15) * 64 + acol0];
        stageA(ktn, cur ^ 1);
        __builtin_amdgcn_s_setprio(1);
#pragma unroll
        for (int mi = 0; mi < 8; ++mi) {
            acc[mi][0] = __builtin_amdgcn_mfma_f32_16x16x32_bf16(a[mi], b0, acc[mi][0], 0, 0, 0);
            acc[mi][1] = __builtin_amdgcn_mfma_f32_16x16x32_bf16(a[mi], b1, acc[mi][1], 0, 0, 0);
        }
        __builtin_amdgcn_s_setprio(0);

        // ---- step 1: kh0, n-frags 2,3 ----
        b0 = *(const bf16x8*)&Bp[(bro + 2 * 16 + l15) * 64 + acol0];
        b1 = *(const bf16x8*)&Bp[(bro + 3 * 16 + l15) * 64 + acol0];
        stageB(ktn, cur ^ 1);
        __builtin_amdgcn_s_setprio(1);
#pragma unroll
        for (int mi = 0; mi < 8; ++mi) {
            acc[mi][2] = __builtin_amdgcn_mfma_f32_16x16x32_bf16(a[mi], b0, acc[mi][2], 0, 0, 0);
            acc[mi][3] = __builtin_amdgcn_mfma_f32_16x16x32_bf16(a[mi], b1, acc[mi][3], 0, 0, 0);
        }
        __builtin_amdgcn_s_setprio(0);

        // ---- step 2: kh1, n-frags 0,1 ----
#pragma unroll
        for (int mi = 0; mi < 8; ++mi) a[mi] = *(const bf16x8*)&Ap[(mi * 16 + l15) * 64 + acol1];
        b0 = *(const bf16x8*)&Bp[(bro + 0 * 16 + l15) * 64 + acol1];
        b1 = *(const bf16x8*)&Bp[(bro + 1 * 16 + l15) * 64 + acol1];
        __builtin_amdgcn_s_setprio(1);
#pragma unroll
        for (int mi = 0; mi < 8; ++mi) {
            acc[mi][0] = __builtin_amdgcn_mfma_f32_16x16x32_bf16(a[mi], b0, acc[mi][0], 0, 0, 0);
            acc[mi][1] = __builtin_amdgcn_mfma_f32_16x16x32_bf16(a[mi], b1, acc[mi][1], 0, 0, 0);
        }
        __builtin_amdgcn_s_setprio(0);

        // ---- step 3: kh1, n-frags 2,3 ----
        b0 = *(const bf16x8*)&Bp[(bro + 2 * 16 + l15) * 64 + acol1];
        b1 = *(const bf16x8*)&Bp[(bro + 3 * 16 + l15) * 64 + acol1];
        __builtin_amdgcn_s_setprio(1);
#pragma unroll
        for (int mi = 0; mi < 8; ++mi) {
            acc[mi][2] = __builtin_amdgcn_mfma_f32_16x16x32_bf16(a[mi], b0, acc[mi][2], 0, 0, 0);
            acc[mi][3] = __builtin_amdgcn_mfma_f32_16x16x32_bf16(a[mi], b1, acc[mi][3], 0, 0, 0);
        }
        __builtin_amdgcn_s_setprio(0);

        // tile boundary: drain own stage loads (~3 steps old) + barrier, all in one
        __syncthreads();
    }

    const int r4 = ((lane >> 4) << 2);
#pragma unroll
    for (int mi = 0; mi < 8; ++mi) {
#pragma unroll
        for (int nj = 0; nj < 4; ++nj) {
            const int col = blockN + wc * 64 + nj * 16 + l15;
            const int row0 = bx * 256 + wr * 128 + mi * 16 + r4;
            if constexpr (MODE == 0) {
                float bias = conv_b[col];
#pragma unroll
                for (int r = 0; r < 4; ++r)
                    outb[(size_t)(row0 + r) * C_ + col] = f2bf(tanhf(acc[mi][nj][r] + bias));
            } else {
#pragma unroll
                for (int r = 0; r < 4; ++r)
                    outf[(size_t)(row0 + r) * C_ + col] = acc[mi][nj][r];
            }
        }
    }
}

// ---------------- column softmax over L + weighted max -> wo[b,c]
__global__ __launch_bounds__(256) void softmax_wo_kernel(
    const float* __restrict__ P, const unsigned short* __restrict__ sent,
    float* __restrict__ wo) {
    const int b = blockIdx.x;
    const int c = blockIdx.y * 256 + threadIdx.x;
    const float* Pb = P + ((size_t)(b << 8)) * C_ + c;
    const unsigned short* Sb = sent + ((size_t)(b << 8)) * C_ + c;
    float m = -INFINITY;
    for (int l = 0; l < L_; ++l) m = fmaxf(m, Pb[(size_t)l * C_]);
    float z = 0.f, wmax = -INFINITY;
    for (int l = 0; l < L_; ++l) {
        float e = expf(Pb[(size_t)l * C_] - m);
        z += e;
        wmax = fmaxf(wmax, bf2f(Sb[(size_t)l * C_]) * e);
    }
    wo[b * C_ + c] = wmax / z;
}

// ---------------- normalize + distances
__global__ __launch_bounds__(256) void final_kernel(
    const float* __restrict__ wo, const float* __restrict__ re, float* __restrict__ out) {
    const int b = blockIdx.x, tid = threadIdx.x;
    __shared__ float won[C_];
    __shared__ float red[256];
    float p = 0.f;
    for (int c = tid; c < C_; c += 256) {
        float v = wo[b * C_ + c];
        p += v * v;
    }
    red[tid] = p; __syncthreads();
    for (int st = 128; st > 0; st >>= 1) {
        if (tid < st) red[tid] += red[tid + st];
        __syncthreads();
    }
    float inv = 1.f / fmaxf(sqrtf(red[0]), 1e-12f);
    for (int c = tid; c < C_; c += 256) won[c] = wo[b * C_ + c] * inv;
    __syncthreads();
    const int wv = tid >> 6, lane = tid & 63;
    for (int r = wv; r < R_; r += 4) {
        float acc2 = 0.f;
        for (int c = lane; c < C_; c += 64) {
            float dlt = won[c] - re[r * C_ + c];
            acc2 += dlt * dlt;
        }
        for (int off = 32; off > 0; off >>= 1) acc2 += __shfl_down(acc2, off);
        if (lane == 0) out[b * R_ + r] = sqrtf(acc2);
    }
}

// ---------------- launch ----------------
extern "C" void kernel_launch(void* const* d_in, const int* in_sizes, int n_in,
                              void* d_out, int out_size, void* d_ws, size_t ws_size,
                              hipStream_t stream) {
    const int* context     = (const int*)d_in[0];
    const int* subject_idx = (const int*)d_in[1];
    const int* object_idx  = (const int*)d_in[2];
    const int* subject_dis = (const int*)d_in[3];
    const int* object_dis  = (const int*)d_in[4];
    const float* embed_table = (const float*)d_in[5];
    const float* pos_table   = (const float*)d_in[6];
    const float* conv_w      = (const float*)d_in[7];
    const float* conv_b      = (const float*)d_in[8];
    const float* rlw         = (const float*)d_in[9];
    const float* re          = (const float*)d_in[10];
    float* out = (float*)d_out;

    char* ws = (char*)d_ws;
    size_t off = 0;
    auto alloc = [&](size_t bytes) {
        void* p = ws + off;
        off = (off + bytes + 255) & ~(size_t)255;
        return p;
    };
    float* wf            = (float*)alloc((size_t)M_ * D_ * 4);            // 52.4 MB
    float* s             = (float*)alloc((size_t)M_ * 4);                 // 0.13 MB
    unsigned short* XSp  = (unsigned short*)alloc((size_t)B_ * LROWS_ * KP_ * 2); // 80.3 MB
    unsigned short* WpT  = (unsigned short*)alloc((size_t)C_ * K3_ * 2);  // 3.7 MB
    unsigned short* MmatT= (unsigned short*)alloc((size_t)C_ * C_ * 2);   // 0.5 MB
    unsigned short* sent = (unsigned short*)alloc((size_t)M_ * C_ * 2);   // 33.6 MB
    float* wo            = (float*)alloc((size_t)B_ * C_ * 4);            // 0.26 MB
    float* SS            = (float*)alloc((size_t)B_ * 3 * D_ * 4);        // 0.61 MB
    float* OS            = (float*)alloc((size_t)B_ * 3 * D_ * 4);        // 0.61 MB
    float* dsb           = (float*)alloc((size_t)M_ * 4);                 // 0.13 MB
    float* ddb           = (float*)alloc((size_t)M_ * 4);                 // 0.13 MB
    // aliases (sequenced so each is fully written before read, dead before overwrite):
    float* Pref = (float*)XSp;  // 52.4 MB prefix sums; dead after span_mean
    float* P    = (float*)XSp;  // 67 MB; XSp dead after conv gemm

    // allow 128KB dynamic LDS for the role-split GEMMs (idempotent, every call)
    (void)hipFuncSetAttribute((const void*)gemm8_kernel<0>,
                              hipFuncAttributeMaxDynamicSharedMemorySize, 131072);
    (void)hipFuncSetAttribute((const void*)gemm8_kernel<1>,
                              hipFuncAttributeMaxDynamicSharedMemorySize, 131072);

    prep_wpT_kernel<<<(C_ * K3_ + 255) / 256, 256, 0, stream>>>(conv_w, WpT);
    prep_mT_kernel<<<(C_ * C_ + 255) / 256, 256, 0, stream>>>(rlw, re, MmatT);
    build_wf_kernel<<<4096, 256, 0, stream>>>(context, subject_dis, object_dis,
                                              embed_table, pos_table, wf);
    // attention-scale phase (parallel)
    prefix_wf_kernel<<<(B_ * D_ + 255) / 256, 256, 0, stream>>>(wf, Pref);
    span_mean_kernel<<<(B_ * 3 * D_ + 255) / 256, 256, 0, stream>>>(Pref, subject_idx,
                                                                    object_idx, SS, OS);
    dots_kernel<<<M_ / 4, 256, 0, stream>>>(wf, SS, OS, dsb, ddb);
    softmax_s_kernel<<<B_, 256, 0, stream>>>(dsb, ddb, s);
    // conv input
    build_xsp_kernel<<<(B_ * LROWS_ * (KP_ / 8) + 255) / 256, 256, 0, stream>>>(wf, s, XSp);
    // conv -> sent (role-split MFMA)
    gemm8_kernel<0><<<dim3(M_ / 256, C_ / 256), 512, 131072, stream>>>(
        XSp, WpT, conv_b, sent, nullptr);
    // P = sent @ Mmat (role-split MFMA)
    gemm8_kernel<1><<<dim3(M_ / 256, C_ / 256), 512, 131072, stream>>>(
        sent, MmatT, nullptr, nullptr, P);
    // softmax over L + weighted max
    softmax_wo_kernel<<<dim3(B_, 2), 256, 0, stream>>>(P, sent, wo);
    // normalize + distances
    final_kernel<<<B_, 256, 0, stream>>>(wo, re, out);
}